// Round 1
// baseline (1406.414 us; speedup 1.0000x reference)
//
#include <hip/hip_runtime.h>
#include <cstdint>
#include <cstddef>

#define B_   256
#define T_   14
#define INF_ 2048
#define H_   512
#define HW_  49
#define NG_  2048   /* 4*H */
#define KC_  1024   /* H (h) + H (c) */

typedef __attribute__((ext_vector_type(8))) _Float16 f16x8;
typedef __attribute__((ext_vector_type(4))) float f32x4;
typedef _Float16 f16;

typedef const void __attribute__((address_space(1))) gvoid_t;
typedef void __attribute__((address_space(3))) svoid_t;

__device__ __forceinline__ void async16(const void* g, void* l) {
  __builtin_amdgcn_global_load_lds((gvoid_t*)g, (svoid_t*)l, 16, 0, 0);
}

__device__ __forceinline__ float sigm(float x) { return 1.0f / (1.0f + __expf(-x)); }

// ---------------- prep: weight conversions + fixation dtype detect ----------------
__global__ void k_prep(const float* __restrict__ Wx, const float* __restrict__ Wh,
                       const float* __restrict__ Wc, const float* __restrict__ bh,
                       const float* __restrict__ bc, const int* __restrict__ fix,
                       f16* __restrict__ Wxh, f16* __restrict__ Wbig,
                       f16* __restrict__ Wc2h, float* __restrict__ biasb,
                       int* __restrict__ flag64)
{
  __shared__ int any;
  const int tid = blockIdx.x * blockDim.x + threadIdx.x;
  const int nth = gridDim.x * blockDim.x;
  if (blockIdx.x == 0) {
    if (threadIdx.x == 0) any = 0;
    __syncthreads();
    int a = 0;
    for (int j = 1 + 2 * (int)threadIdx.x; j < B_ * T_; j += 2 * (int)blockDim.x) a |= fix[j];
    if (a) any = 1;
    __syncthreads();
    if (threadIdx.x == 0) flag64[0] = (any == 0) ? 1 : 0;
  }
  for (int i = tid; i < 4 * H_ * INF_; i += nth) Wxh[i] = (f16)Wx[i];
  for (int i = tid; i < NG_ * KC_; i += nth) {
    const int n = i >> 10, k = i & 1023;
    const int g = n >> 9, h = n & 511;
    float v;
    if (k < H_) v = Wh[(size_t)n * H_ + k];
    else {
      const int kk = k - H_;
      v = (g == 0) ? Wc[h * H_ + kk] : (g == 1) ? Wc[H_ * H_ + h * H_ + kk] : 0.0f;
    }
    Wbig[i] = (f16)v;
  }
  for (int i = tid; i < H_ * H_; i += nth) Wc2h[i] = (f16)Wc[2 * H_ * H_ + i];
  for (int i = tid; i < NG_; i += nth) {
    const int g = i >> 9, h = i & 511;
    biasb[i] = bh[i] + ((g == 0) ? bc[h] : (g == 1) ? bc[H_ + h] : 0.0f);
  }
}

// ---------------- gather fixated columns -> f16 xg [B*T][IN], + tlast ----------------
__global__ void k_gather(const float* __restrict__ x, const int* __restrict__ fix,
                         const int* __restrict__ flag64, f16* __restrict__ xg,
                         int* __restrict__ tlast)
{
  const int b = blockIdx.x;
  const int i0 = blockIdx.y * 512;
  const int tid = threadIdx.x;
  const int is64 = flag64[0];
  if (blockIdx.y == 0 && tid == 0) {
    int cnt = 0;
    for (int t = 0; t < T_; ++t) {
      const int w = is64 ? fix[2 * (b * T_ + t)] : fix[b * T_ + t];
      cnt += (w == 0);
    }
    tlast[b] = (cnt < T_) ? (T_ - 1 - cnt) : (T_ - 1);
  }
  for (int t = 0; t < T_; ++t) {
    const int w = is64 ? fix[2 * (b * T_ + t)] : fix[b * T_ + t];
    const float* xb = x + ((size_t)b * INF_) * HW_ + w;
    f16* dst = xg + (size_t)(b * T_ + t) * INF_;
    for (int i = i0 + tid; i < i0 + 512; i += 256) dst[i] = (f16)xb[(size_t)i * HW_];
  }
}

// ---------------- big GEMM: xproj[M=3584][N=2048] = xg @ Wx^T + bx ----------------
__global__ __launch_bounds__(256) void k_gemm_big(
    const f16* __restrict__ A, const f16* __restrict__ Bw,
    const float* __restrict__ bx, float* __restrict__ Cproj)
{
  __shared__ alignas(16) f16 As[128 * 64];
  __shared__ alignas(16) f16 Bs[128 * 64];
  const int tid = threadIdx.x;
  const int lane = tid & 63;
  const int w = tid >> 6;
  const int wm = w >> 1, wn = w & 1;
  const int m0 = blockIdx.y * 128, n0 = blockIdx.x * 128;
  f32x4 acc[4][4] = {};
  const int lrow = lane >> 3;
  const int kg = lane & 7;
  for (int ks = 0; ks < 2048; ks += 64) {
#pragma unroll
    for (int q = 0; q < 4; ++q) {
      const int chunk = (w << 2) + q;
      const int row = (chunk << 3) + lrow;
      const int skg = kg ^ (row & 7);
      async16(A + (size_t)(m0 + row) * 2048 + ks + (skg << 3), As + chunk * 512);
      async16(Bw + (size_t)(n0 + row) * 2048 + ks + (skg << 3), Bs + chunk * 512);
    }
    __syncthreads();
#pragma unroll
    for (int kk = 0; kk < 2; ++kk) {
      const int kgl = (kk << 2) + (lane >> 4);
      f16x8 af[4], bf[4];
#pragma unroll
      for (int mi = 0; mi < 4; ++mi) {
        const int r = (wm << 6) + (mi << 4) + (lane & 15);
        af[mi] = *(const f16x8*)(As + r * 64 + ((kgl ^ (r & 7)) << 3));
      }
#pragma unroll
      for (int ni = 0; ni < 4; ++ni) {
        const int r = (wn << 6) + (ni << 4) + (lane & 15);
        bf[ni] = *(const f16x8*)(Bs + r * 64 + ((kgl ^ (r & 7)) << 3));
      }
#pragma unroll
      for (int mi = 0; mi < 4; ++mi)
#pragma unroll
        for (int ni = 0; ni < 4; ++ni)
          acc[mi][ni] = __builtin_amdgcn_mfma_f32_16x16x32_f16(af[mi], bf[ni], acc[mi][ni], 0, 0, 0);
    }
    __syncthreads();
  }
#pragma unroll
  for (int mi = 0; mi < 4; ++mi)
#pragma unroll
    for (int ni = 0; ni < 4; ++ni)
#pragma unroll
      for (int r4 = 0; r4 < 4; ++r4) {
        const int row = m0 + (wm << 6) + (mi << 4) + ((lane >> 4) << 2) + r4;
        const int col = n0 + (wn << 6) + (ni << 4) + (lane & 15);
        Cproj[(size_t)row * 2048 + col] = acc[mi][ni][r4] + bx[col];
      }
}

// ---------------- gates GEMM: lin[b][4H] = [h|c] @ Wbig^T + biasb + xproj[b*T+t] ----------------
__global__ __launch_bounds__(256) void k_gemm_gates(
    const f16* __restrict__ Hc, const f16* __restrict__ Wbig,
    const float* __restrict__ biasb, const float* __restrict__ xproj,
    float* __restrict__ lin, const int t)
{
  __shared__ alignas(16) f16 As[64 * 64];
  __shared__ alignas(16) f16 Bs[64 * 64];
  const int tid = threadIdx.x;
  const int lane = tid & 63;
  const int w = tid >> 6;
  const int wm = w >> 1, wn = w & 1;
  const int m0 = blockIdx.y * 64, n0 = blockIdx.x * 64;
  f32x4 acc[2][2] = {};
  const int lrow = lane >> 3;
  const int kg = lane & 7;
  for (int ks = 0; ks < KC_; ks += 64) {
#pragma unroll
    for (int q = 0; q < 2; ++q) {
      const int chunk = (w << 1) + q;
      const int row = (chunk << 3) + lrow;
      const int skg = kg ^ (row & 7);
      async16(Hc + (size_t)(m0 + row) * KC_ + ks + (skg << 3), As + chunk * 512);
      async16(Wbig + (size_t)(n0 + row) * KC_ + ks + (skg << 3), Bs + chunk * 512);
    }
    __syncthreads();
#pragma unroll
    for (int kk = 0; kk < 2; ++kk) {
      const int kgl = (kk << 2) + (lane >> 4);
      f16x8 af[2], bf[2];
#pragma unroll
      for (int mi = 0; mi < 2; ++mi) {
        const int r = (wm << 5) + (mi << 4) + (lane & 15);
        af[mi] = *(const f16x8*)(As + r * 64 + ((kgl ^ (r & 7)) << 3));
      }
#pragma unroll
      for (int ni = 0; ni < 2; ++ni) {
        const int r = (wn << 5) + (ni << 4) + (lane & 15);
        bf[ni] = *(const f16x8*)(Bs + r * 64 + ((kgl ^ (r & 7)) << 3));
      }
#pragma unroll
      for (int mi = 0; mi < 2; ++mi)
#pragma unroll
        for (int ni = 0; ni < 2; ++ni)
          acc[mi][ni] = __builtin_amdgcn_mfma_f32_16x16x32_f16(af[mi], bf[ni], acc[mi][ni], 0, 0, 0);
    }
    __syncthreads();
  }
#pragma unroll
  for (int mi = 0; mi < 2; ++mi)
#pragma unroll
    for (int ni = 0; ni < 2; ++ni)
#pragma unroll
      for (int r4 = 0; r4 < 4; ++r4) {
        const int row = m0 + (wm << 5) + (mi << 4) + ((lane >> 4) << 2) + r4;
        const int col = n0 + (wn << 5) + (ni << 4) + (lane & 15);
        lin[row * 2048 + col] = acc[mi][ni][r4] + biasb[col]
                              + xproj[((size_t)row * T_ + t) * 2048 + col];
      }
}

// ---------------- out GEMM: c update + o peephole + h write + last-h select ----------------
__global__ __launch_bounds__(256) void k_gemm_outc(
    const float* __restrict__ lin, const f16* __restrict__ Wc2h,
    const float* __restrict__ bc, const float* __restrict__ cold,
    float* __restrict__ cnew, f16* __restrict__ hcat,
    float* __restrict__ lasth, const int* __restrict__ tlast, const int t)
{
  __shared__ alignas(16) f16 As[64 * 64];
  __shared__ alignas(16) f16 Bs[64 * 64];
  const int tid = threadIdx.x;
  const int lane = tid & 63;
  const int w = tid >> 6;
  const int wm = w >> 1, wn = w & 1;
  const int m0 = blockIdx.y * 64, n0 = blockIdx.x * 64;
  f32x4 acc[2][2] = {};
  const int lrow = lane >> 3;
  const int kg = lane & 7;
  for (int ks = 0; ks < H_; ks += 64) {
#pragma unroll
    for (int q = 0; q < 2; ++q) {
      // A operand: compute c_new tile on the fly, store swizzled
      const int oid = tid + q * 256;
      const int row = oid >> 3;
      const int kgo = oid & 7;
      const int b = m0 + row;
      const int k = ks + (kgo << 3);
      f16x8 v;
#pragma unroll
      for (int j = 0; j < 8; ++j) {
        const int kj = k + j;
        const float ci = sigm(lin[b * 2048 + kj]);
        const float cf = sigm(lin[b * 2048 + 512 + kj]);
        const float cg = tanhf(lin[b * 2048 + 1536 + kj]);
        const float cn = ci * cg + cf * cold[b * 512 + kj];
        v[j] = (f16)cn;
      }
      *(f16x8*)(As + row * 64 + ((kgo ^ (row & 7)) << 3)) = v;
      // B operand: Wc[2] via async load, source-swizzled
      const int chunk = (w << 1) + q;
      const int rowb = (chunk << 3) + lrow;
      const int skg = kg ^ (rowb & 7);
      async16(Wc2h + (size_t)(n0 + rowb) * H_ + ks + (skg << 3), Bs + chunk * 512);
    }
    __syncthreads();
#pragma unroll
    for (int kk = 0; kk < 2; ++kk) {
      const int kgl = (kk << 2) + (lane >> 4);
      f16x8 af[2], bf[2];
#pragma unroll
      for (int mi = 0; mi < 2; ++mi) {
        const int r = (wm << 5) + (mi << 4) + (lane & 15);
        af[mi] = *(const f16x8*)(As + r * 64 + ((kgl ^ (r & 7)) << 3));
      }
#pragma unroll
      for (int ni = 0; ni < 2; ++ni) {
        const int r = (wn << 5) + (ni << 4) + (lane & 15);
        bf[ni] = *(const f16x8*)(Bs + r * 64 + ((kgl ^ (r & 7)) << 3));
      }
#pragma unroll
      for (int mi = 0; mi < 2; ++mi)
#pragma unroll
        for (int ni = 0; ni < 2; ++ni)
          acc[mi][ni] = __builtin_amdgcn_mfma_f32_16x16x32_f16(af[mi], bf[ni], acc[mi][ni], 0, 0, 0);
    }
    __syncthreads();
  }
#pragma unroll
  for (int mi = 0; mi < 2; ++mi)
#pragma unroll
    for (int ni = 0; ni < 2; ++ni)
#pragma unroll
      for (int r4 = 0; r4 < 4; ++r4) {
        const int m = m0 + (wm << 5) + (mi << 4) + ((lane >> 4) << 2) + r4;
        const int col = n0 + (wn << 5) + (ni << 4) + (lane & 15);
        const float ci = sigm(lin[m * 2048 + col]);
        const float cf = sigm(lin[m * 2048 + 512 + col]);
        const float cg = tanhf(lin[m * 2048 + 1536 + col]);
        const float cn = ci * cg + cf * cold[m * 512 + col];
        const float ol = acc[mi][ni][r4] + lin[m * 2048 + 1024 + col] + bc[2 * H_ + col];
        const float o = sigm(ol);
        const float h = o * cn;
        cnew[m * 512 + col] = cn;
        hcat[m * 1024 + col] = (f16)h;
        hcat[m * 1024 + 512 + col] = (f16)cn;
        if (t == tlast[m]) lasth[m * 512 + col] = h;
      }
}

// ---------------- final: out[b] = sigmoid(last_h . Wd + bd) ----------------
__global__ void k_final(const float* __restrict__ lasth, const float* __restrict__ Wd,
                        const float* __restrict__ bd, float* __restrict__ out)
{
  const int b = blockIdx.x;
  const int lane = threadIdx.x;
  float s = 0.f;
  for (int k = lane; k < H_; k += 64) s += lasth[b * H_ + k] * Wd[k];
#pragma unroll
  for (int off = 32; off > 0; off >>= 1) s += __shfl_down(s, off);
  if (lane == 0) out[b] = 1.0f / (1.0f + __expf(-(s + bd[0])));
}

extern "C" void kernel_launch(void* const* d_in, const int* in_sizes, int n_in,
                              void* d_out, int out_size, void* d_ws, size_t ws_size,
                              hipStream_t stream) {
  const float* x   = (const float*)d_in[0];
  const int*   fix = (const int*)d_in[1];
  const float* Wx  = (const float*)d_in[2];
  const float* bx  = (const float*)d_in[3];
  const float* Wh  = (const float*)d_in[4];
  const float* bh  = (const float*)d_in[5];
  const float* Wc  = (const float*)d_in[6];
  const float* bc  = (const float*)d_in[7];
  const float* Wd  = (const float*)d_in[8];
  const float* bd  = (const float*)d_in[9];
  float* out = (float*)d_out;
  char* ws = (char*)d_ws;

  f16*   xg    = (f16*)(ws);                       // 14,680,064 B
  f16*   Wxh   = (f16*)(ws + 14680064);            //  8,388,608
  float* xproj = (float*)(ws + 23068672);          // 29,360,128
  f16*   Wbig  = (f16*)(ws + 52428800);            //  4,194,304
  f16*   Wc2h  = (f16*)(ws + 56623104);            //    524,288
  float* biasb = (float*)(ws + 57147392);          //      8,192
  f16*   hcat  = (f16*)(ws + 57155584);            //    524,288
  float* c0    = (float*)(ws + 57679872);          //    524,288
  float* c1    = (float*)(ws + 58204160);          //    524,288
  float* lin   = (float*)(ws + 58728448);          //  2,097,152
  float* lasth = (float*)(ws + 60825600);          //    524,288
  int*   tlast = (int*)(ws + 61349888);            //      1,024
  int*   flag64= (int*)(ws + 61350912);            //          4

  hipMemsetAsync(hcat, 0, 256 * 1024 * sizeof(f16), stream);
  hipMemsetAsync(c0, 0, 256 * 512 * sizeof(float), stream);

  k_prep<<<2048, 256, 0, stream>>>(Wx, Wh, Wc, bh, bc, fix, Wxh, Wbig, Wc2h, biasb, flag64);
  k_gather<<<dim3(256, 4), 256, 0, stream>>>(x, fix, flag64, xg, tlast);
  k_gemm_big<<<dim3(16, 28), 256, 0, stream>>>(xg, Wxh, bx, xproj);
  for (int t = 0; t < T_; ++t) {
    float* cold = (t & 1) ? c1 : c0;
    float* cnew = (t & 1) ? c0 : c1;
    k_gemm_gates<<<dim3(32, 4), 256, 0, stream>>>(hcat, Wbig, biasb, xproj, lin, t);
    k_gemm_outc<<<dim3(8, 4), 256, 0, stream>>>(lin, Wc2h, bc, cold, cnew, hcat, lasth, tlast, t);
  }
  k_final<<<256, 64, 0, stream>>>(lasth, Wd, bd, out);
}

// Round 2
// 1207.852 us; speedup vs baseline: 1.1644x; 1.1644x over previous
//
#include <hip/hip_runtime.h>
#include <cstdint>
#include <cstddef>

#define B_   256
#define T_   14
#define INF_ 2048
#define H_   512
#define HW_  49
#define NG_  2048   /* 4*H */
#define KC_  1024   /* H (h) + H (c) */

typedef __attribute__((ext_vector_type(8))) _Float16 f16x8;
typedef __attribute__((ext_vector_type(4))) float f32x4;
typedef _Float16 f16;

typedef const void __attribute__((address_space(1))) gvoid_t;
typedef void __attribute__((address_space(3))) svoid_t;

__device__ __forceinline__ void async16(const void* g, void* l) {
  __builtin_amdgcn_global_load_lds((gvoid_t*)g, (svoid_t*)l, 16, 0, 0);
}

__device__ __forceinline__ float sigm(float x) { return 1.0f / (1.0f + __expf(-x)); }

// ---------------- prep: weight conversions (gate-interleaved n = h*4+g) ----------------
__global__ void k_prep(const float* __restrict__ Wx, const float* __restrict__ bx,
                       const float* __restrict__ Wh, const float* __restrict__ Wc,
                       const float* __restrict__ bh, const float* __restrict__ bc,
                       const int* __restrict__ fix,
                       f16* __restrict__ Wxh, float* __restrict__ bxp,
                       f16* __restrict__ Wbig, f16* __restrict__ Wc2h,
                       float* __restrict__ biasb, int* __restrict__ flag64)
{
  __shared__ int any;
  const int tid = blockIdx.x * blockDim.x + threadIdx.x;
  const int nth = gridDim.x * blockDim.x;
  if (blockIdx.x == 0) {
    if (threadIdx.x == 0) any = 0;
    __syncthreads();
    int a = 0;
    for (int j = 1 + 2 * (int)threadIdx.x; j < B_ * T_; j += 2 * (int)blockDim.x) a |= fix[j];
    if (a) any = 1;
    __syncthreads();
    if (threadIdx.x == 0) flag64[0] = (any == 0) ? 1 : 0;
  }
  // Wxh: row n = h*4+g  <- Wx[g][h][:]
  for (int i = tid; i < 4 * H_ * INF_; i += nth) {
    const int n = i >> 11, k = i & 2047;
    const int g = n & 3, h = n >> 2;
    Wxh[i] = (f16)Wx[((size_t)(g * H_ + h)) * INF_ + k];
  }
  // Wbig: row n = h*4+g, k<512: Wh[g][h][k]; k>=512: peephole (g0,g1) else 0
  for (int i = tid; i < NG_ * KC_; i += nth) {
    const int n = i >> 10, k = i & 1023;
    const int g = n & 3, h = n >> 2;
    float v;
    if (k < H_) v = Wh[((size_t)(g * H_ + h)) * H_ + k];
    else {
      const int kk = k - H_;
      v = (g == 0) ? Wc[h * H_ + kk] : (g == 1) ? Wc[H_ * H_ + h * H_ + kk] : 0.0f;
    }
    Wbig[i] = (f16)v;
  }
  for (int i = tid; i < H_ * H_; i += nth) Wc2h[i] = (f16)Wc[2 * H_ * H_ + i];
  for (int i = tid; i < NG_; i += nth) {
    const int g = i & 3, h = i >> 2;
    biasb[i] = bh[g * H_ + h] + ((g == 0) ? bc[h] : (g == 1) ? bc[H_ + h] : 0.0f);
    bxp[i] = bx[g * H_ + h];
  }
}

// ---------------- gather: coalesced row-read, extract 14 columns from LDS ----------------
// grid (256 b, 4), each block handles 2 chunks of 256 rows
__global__ __launch_bounds__(256) void k_gather(const float* __restrict__ x,
                                                const int* __restrict__ fix,
                                                const int* __restrict__ flag64,
                                                f16* __restrict__ xg,
                                                int* __restrict__ tlast)
{
  __shared__ float rows[256 * 49];   // 50176 B
  __shared__ int wv[T_];
  const int b = blockIdx.x;
  const int tid = threadIdx.x;
  const int is64 = flag64[0];
  if (tid < T_) wv[tid] = is64 ? fix[2 * (b * T_ + tid)] : fix[b * T_ + tid];
  __syncthreads();
  if (blockIdx.y == 0 && tid == 0) {
    int cnt = 0;
    for (int t = 0; t < T_; ++t) cnt += (wv[t] == 0);
    tlast[b] = (cnt < T_) ? (T_ - 1 - cnt) : (T_ - 1);
  }
  const float* xb = x + (size_t)b * (INF_ * HW_);
  for (int c = 0; c < 2; ++c) {
    const int ch = blockIdx.y * 2 + c;
    if (c) __syncthreads();
    const float4* src = (const float4*)(xb + (size_t)ch * 256 * 49);
    float4* dst4 = (float4*)rows;
    for (int i = tid; i < 3136; i += 256) dst4[i] = src[i];
    __syncthreads();
#pragma unroll
    for (int t = 0; t < T_; ++t)
      xg[(size_t)(b * T_ + t) * INF_ + ch * 256 + tid] = (f16)rows[tid * 49 + wv[t]];
  }
}

// ---------------- big GEMM: xproj[M=3584][N=2048] = xg @ Wxh^T + bxp ----------------
__global__ __launch_bounds__(256) void k_gemm_big(
    const f16* __restrict__ A, const f16* __restrict__ Bw,
    const float* __restrict__ bxp, float* __restrict__ Cproj)
{
  __shared__ alignas(16) f16 As[128 * 64];
  __shared__ alignas(16) f16 Bs[128 * 64];
  const int tid = threadIdx.x;
  const int lane = tid & 63;
  const int w = tid >> 6;
  const int wm = w >> 1, wn = w & 1;
  // XCD-bijective swizzle (448 blocks, 448%8==0, q=56)
  const int flat = blockIdx.y * 16 + blockIdx.x;
  const int wg = (flat & 7) * 56 + (flat >> 3);
  const int m0 = (wg >> 4) * 128, n0 = (wg & 15) * 128;
  f32x4 acc[4][4] = {};
  const int lrow = lane >> 3;
  const int kg = lane & 7;
  for (int ks = 0; ks < 2048; ks += 64) {
#pragma unroll
    for (int q = 0; q < 4; ++q) {
      const int chunk = (w << 2) + q;
      const int row = (chunk << 3) + lrow;
      const int skg = kg ^ (row & 7);
      async16(A + (size_t)(m0 + row) * 2048 + ks + (skg << 3), As + chunk * 512);
      async16(Bw + (size_t)(n0 + row) * 2048 + ks + (skg << 3), Bs + chunk * 512);
    }
    __syncthreads();
#pragma unroll
    for (int kk = 0; kk < 2; ++kk) {
      const int kgl = (kk << 2) + (lane >> 4);
      f16x8 af[4], bf[4];
#pragma unroll
      for (int mi = 0; mi < 4; ++mi) {
        const int r = (wm << 6) + (mi << 4) + (lane & 15);
        af[mi] = *(const f16x8*)(As + r * 64 + ((kgl ^ (r & 7)) << 3));
      }
#pragma unroll
      for (int ni = 0; ni < 4; ++ni) {
        const int r = (wn << 6) + (ni << 4) + (lane & 15);
        bf[ni] = *(const f16x8*)(Bs + r * 64 + ((kgl ^ (r & 7)) << 3));
      }
#pragma unroll
      for (int mi = 0; mi < 4; ++mi)
#pragma unroll
        for (int ni = 0; ni < 4; ++ni)
          acc[mi][ni] = __builtin_amdgcn_mfma_f32_16x16x32_f16(af[mi], bf[ni], acc[mi][ni], 0, 0, 0);
    }
    __syncthreads();
  }
#pragma unroll
  for (int mi = 0; mi < 4; ++mi)
#pragma unroll
    for (int ni = 0; ni < 4; ++ni)
#pragma unroll
      for (int r4 = 0; r4 < 4; ++r4) {
        const int row = m0 + (wm << 6) + (mi << 4) + ((lane >> 4) << 2) + r4;
        const int col = n0 + (wn << 6) + (ni << 4) + (lane & 15);
        Cproj[(size_t)row * 2048 + col] = acc[mi][ni][r4] + bxp[col];
      }
}

// ---------------- gates GEMM (2-phase dbuf): lin[b][n] = [h|c]@Wbig^T + biasb + xproj ----------------
__global__ __launch_bounds__(256) void k_gemm_gates(
    const f16* __restrict__ Hc, const f16* __restrict__ Wbig,
    const float* __restrict__ biasb, const float* __restrict__ xproj,
    float* __restrict__ lin, const int t)
{
  __shared__ alignas(16) f16 As[2][64 * 64];
  __shared__ alignas(16) f16 Bs[2][64 * 64];
  const int tid = threadIdx.x;
  const int lane = tid & 63;
  const int w = tid >> 6;
  const int wm = w >> 1, wn = w & 1;
  const int m0 = blockIdx.y * 64, n0 = blockIdx.x * 64;
  f32x4 acc[2][2] = {};
  const int lrow = lane >> 3;
  const int kg = lane & 7;
  const int srow = (w << 1 << 3) + lrow;      // rows this thread stages (q=0 base)
  auto STAGE = [&](int buf, int ks) {
#pragma unroll
    for (int q = 0; q < 2; ++q) {
      const int row = srow + (q << 3);
      const int skg = kg ^ (row & 7);
      async16(Hc + (size_t)(m0 + row) * KC_ + ks + (skg << 3), &As[buf][row * 64]);
      async16(Wbig + (size_t)(n0 + row) * KC_ + ks + (skg << 3), &Bs[buf][row * 64]);
    }
  };
  STAGE(0, 0);
  __syncthreads();
  for (int it = 0; it < 16; ++it) {
    const int cur = it & 1;
    if (it + 1 < 16) STAGE(cur ^ 1, (it + 1) * 64);
#pragma unroll
    for (int kk = 0; kk < 2; ++kk) {
      const int kgl = (kk << 2) + (lane >> 4);
      f16x8 af[2], bf[2];
#pragma unroll
      for (int mi = 0; mi < 2; ++mi) {
        const int r = (wm << 5) + (mi << 4) + (lane & 15);
        af[mi] = *(const f16x8*)(&As[cur][r * 64 + ((kgl ^ (r & 7)) << 3)]);
      }
#pragma unroll
      for (int ni = 0; ni < 2; ++ni) {
        const int r = (wn << 5) + (ni << 4) + (lane & 15);
        bf[ni] = *(const f16x8*)(&Bs[cur][r * 64 + ((kgl ^ (r & 7)) << 3)]);
      }
#pragma unroll
      for (int mi = 0; mi < 2; ++mi)
#pragma unroll
        for (int ni = 0; ni < 2; ++ni)
          acc[mi][ni] = __builtin_amdgcn_mfma_f32_16x16x32_f16(af[mi], bf[ni], acc[mi][ni], 0, 0, 0);
    }
    __syncthreads();
  }
#pragma unroll
  for (int mi = 0; mi < 2; ++mi)
#pragma unroll
    for (int ni = 0; ni < 2; ++ni)
#pragma unroll
      for (int r4 = 0; r4 < 4; ++r4) {
        const int row = m0 + (wm << 5) + (mi << 4) + ((lane >> 4) << 2) + r4;
        const int col = n0 + (wn << 5) + (ni << 4) + (lane & 15);
        lin[row * 2048 + col] = acc[mi][ni][r4] + biasb[col]
                              + xproj[((size_t)row * T_ + t) * 2048 + col];
      }
}

// ---------------- outc GEMM (2-phase dbuf): c update + o peephole + h write ----------------
__global__ __launch_bounds__(256) void k_gemm_outc(
    const float* __restrict__ lin, const f16* __restrict__ Wc2h,
    const float* __restrict__ bc, const float* __restrict__ cold,
    float* __restrict__ cnew, f16* __restrict__ hcat,
    float* __restrict__ lasth, const int* __restrict__ tlast, const int t)
{
  __shared__ alignas(16) f16 As[2][64 * 64];
  __shared__ alignas(16) f16 Bs[2][64 * 64];
  const int tid = threadIdx.x;
  const int lane = tid & 63;
  const int w = tid >> 6;
  const int wm = w >> 1, wn = w & 1;
  const int m0 = blockIdx.y * 64, n0 = blockIdx.x * 64;
  f32x4 acc[2][2] = {};
  const int lrow = lane >> 3;
  const int kg = lane & 7;
  const float4* linv = (const float4*)lin;   // [b][512] of (i,f,o,m)
  auto STAGE = [&](int buf, int ks) {
#pragma unroll
    for (int q = 0; q < 2; ++q) {
      // A operand: compute c_new tile on the fly, store swizzled
      const int oid = tid + q * 256;
      const int row = oid >> 3;
      const int kgo = oid & 7;
      const int b = m0 + row;
      const int k = ks + (kgo << 3);
      f16x8 v;
#pragma unroll
      for (int j = 0; j < 8; ++j) {
        const int kj = k + j;
        const float4 l4 = linv[b * 512 + kj];
        const float cn = sigm(l4.x) * tanhf(l4.w) + sigm(l4.y) * cold[b * 512 + kj];
        v[j] = (f16)cn;
      }
      *(f16x8*)(&As[buf][row * 64 + ((kgo ^ (row & 7)) << 3)]) = v;
      // B operand: Wc2h via async load, source-swizzled
      const int rowb = (w << 4) + (q << 3) + lrow;
      const int skg = kg ^ (rowb & 7);
      async16(Wc2h + (size_t)(n0 + rowb) * H_ + ks + (skg << 3), &Bs[buf][rowb * 64]);
    }
  };
  STAGE(0, 0);
  __syncthreads();
  for (int it = 0; it < 8; ++it) {
    const int cur = it & 1;
    if (it + 1 < 8) STAGE(cur ^ 1, (it + 1) * 64);
#pragma unroll
    for (int kk = 0; kk < 2; ++kk) {
      const int kgl = (kk << 2) + (lane >> 4);
      f16x8 af[2], bf[2];
#pragma unroll
      for (int mi = 0; mi < 2; ++mi) {
        const int r = (wm << 5) + (mi << 4) + (lane & 15);
        af[mi] = *(const f16x8*)(&As[cur][r * 64 + ((kgl ^ (r & 7)) << 3)]);
      }
#pragma unroll
      for (int ni = 0; ni < 2; ++ni) {
        const int r = (wn << 5) + (ni << 4) + (lane & 15);
        bf[ni] = *(const f16x8*)(&Bs[cur][r * 64 + ((kgl ^ (r & 7)) << 3)]);
      }
#pragma unroll
      for (int mi = 0; mi < 2; ++mi)
#pragma unroll
        for (int ni = 0; ni < 2; ++ni)
          acc[mi][ni] = __builtin_amdgcn_mfma_f32_16x16x32_f16(af[mi], bf[ni], acc[mi][ni], 0, 0, 0);
    }
    __syncthreads();
  }
#pragma unroll
  for (int mi = 0; mi < 2; ++mi)
#pragma unroll
    for (int ni = 0; ni < 2; ++ni)
#pragma unroll
      for (int r4 = 0; r4 < 4; ++r4) {
        const int m = m0 + (wm << 5) + (mi << 4) + ((lane >> 4) << 2) + r4;
        const int col = n0 + (wn << 5) + (ni << 4) + (lane & 15);
        const float4 l4 = linv[m * 512 + col];
        const float cn = sigm(l4.x) * tanhf(l4.w) + sigm(l4.y) * cold[m * 512 + col];
        const float o = sigm(acc[mi][ni][r4] + l4.z + bc[2 * H_ + col]);
        const float h = o * cn;
        cnew[m * 512 + col] = cn;
        hcat[m * 1024 + col] = (f16)h;
        hcat[m * 1024 + 512 + col] = (f16)cn;
        if (t == tlast[m]) lasth[m * 512 + col] = h;
      }
}

// ---------------- final: out[b] = sigmoid(last_h . Wd + bd) ----------------
__global__ void k_final(const float* __restrict__ lasth, const float* __restrict__ Wd,
                        const float* __restrict__ bd, float* __restrict__ out)
{
  const int b = blockIdx.x;
  const int lane = threadIdx.x;
  float s = 0.f;
  for (int k = lane; k < H_; k += 64) s += lasth[b * H_ + k] * Wd[k];
#pragma unroll
  for (int off = 32; off > 0; off >>= 1) s += __shfl_down(s, off);
  if (lane == 0) out[b] = 1.0f / (1.0f + __expf(-(s + bd[0])));
}

extern "C" void kernel_launch(void* const* d_in, const int* in_sizes, int n_in,
                              void* d_out, int out_size, void* d_ws, size_t ws_size,
                              hipStream_t stream) {
  const float* x   = (const float*)d_in[0];
  const int*   fix = (const int*)d_in[1];
  const float* Wx  = (const float*)d_in[2];
  const float* bx  = (const float*)d_in[3];
  const float* Wh  = (const float*)d_in[4];
  const float* bh  = (const float*)d_in[5];
  const float* Wc  = (const float*)d_in[6];
  const float* bc  = (const float*)d_in[7];
  const float* Wd  = (const float*)d_in[8];
  const float* bd  = (const float*)d_in[9];
  float* out = (float*)d_out;
  char* ws = (char*)d_ws;

  f16*   xg    = (f16*)(ws);                       // 14,680,064 B
  f16*   Wxh   = (f16*)(ws + 14680064);            //  8,388,608
  float* xproj = (float*)(ws + 23068672);          // 29,360,128
  f16*   Wbig  = (f16*)(ws + 52428800);            //  4,194,304
  f16*   Wc2h  = (f16*)(ws + 56623104);            //    524,288
  float* biasb = (float*)(ws + 57147392);          //      8,192
  f16*   hcat  = (f16*)(ws + 57155584);            //    524,288
  float* c0    = (float*)(ws + 57679872);          //    524,288
  float* c1    = (float*)(ws + 58204160);          //    524,288
  float* lin   = (float*)(ws + 58728448);          //  2,097,152
  float* lasth = (float*)(ws + 60825600);          //    524,288
  int*   tlast = (int*)(ws + 61349888);            //      1,024
  int*   flag64= (int*)(ws + 61350912);            //          4
  float* bxp   = (float*)(ws + 61351936);          //      8,192

  hipMemsetAsync(hcat, 0, 256 * 1024 * sizeof(f16), stream);
  hipMemsetAsync(c0, 0, 256 * 512 * sizeof(float), stream);

  k_prep<<<2048, 256, 0, stream>>>(Wx, bx, Wh, Wc, bh, bc, fix, Wxh, bxp, Wbig, Wc2h, biasb, flag64);
  k_gather<<<dim3(256, 4), 256, 0, stream>>>(x, fix, flag64, xg, tlast);
  k_gemm_big<<<dim3(16, 28), 256, 0, stream>>>(xg, Wxh, bxp, xproj);
  for (int t = 0; t < T_; ++t) {
    float* cold = (t & 1) ? c1 : c0;
    float* cnew = (t & 1) ? c0 : c1;
    k_gemm_gates<<<dim3(32, 4), 256, 0, stream>>>(hcat, Wbig, biasb, xproj, lin, t);
    k_gemm_outc<<<dim3(8, 4), 256, 0, stream>>>(lin, Wc2h, bc, cold, cnew, hcat, lasth, tlast, t);
  }
  k_final<<<256, 64, 0, stream>>>(lasth, Wd, bd, out);
}

// Round 3
// 1122.688 us; speedup vs baseline: 1.2527x; 1.0759x over previous
//
#include <hip/hip_runtime.h>
#include <cstdint>
#include <cstddef>

#define B_   256
#define T_   14
#define INF_ 2048
#define H_   512
#define HW_  49
#define NG_  2048   /* 4*H */
#define KC_  1024   /* H (h) + H (c) */
#define NBLK 256

typedef __attribute__((ext_vector_type(8))) _Float16 f16x8;
typedef __attribute__((ext_vector_type(4))) float f32x4;
typedef _Float16 f16;

typedef const void __attribute__((address_space(1))) gvoid_t;
typedef void __attribute__((address_space(3))) svoid_t;

__device__ __forceinline__ void async16(const void* g, void* l) {
  __builtin_amdgcn_global_load_lds((gvoid_t*)g, (svoid_t*)l, 16, 0, 0);
}

__device__ __forceinline__ float sigm(float x) { return 1.0f / (1.0f + __expf(-x)); }

// two-level monotonic grid barrier: 16 leaf counters (16 arrivals each) -> root -> gen
__device__ __forceinline__ void gbar(int* __restrict__ bar, const int p, const int bid) {
  __syncthreads();
  if (threadIdx.x == 0) {
    __threadfence();
    int* leaf = bar + ((bid & 15) << 5);   // 128 B apart
    int* root = bar + 512;
    int* gen  = bar + 544;
    bool release = false;
    if (__hip_atomic_fetch_add(leaf, 1, __ATOMIC_ACQ_REL, __HIP_MEMORY_SCOPE_AGENT) == (p << 4) + 15) {
      if (__hip_atomic_fetch_add(root, 1, __ATOMIC_ACQ_REL, __HIP_MEMORY_SCOPE_AGENT) == (p << 4) + 15) {
        __hip_atomic_store(gen, p + 1, __ATOMIC_RELEASE, __HIP_MEMORY_SCOPE_AGENT);
        release = true;
      }
    }
    if (!release) {
      while (__hip_atomic_load(gen, __ATOMIC_ACQUIRE, __HIP_MEMORY_SCOPE_AGENT) <= p)
        __builtin_amdgcn_s_sleep(2);
    }
    __threadfence();
  }
  __syncthreads();
}

// ---------------- prep: weight conversions (gate-interleaved n = h*4+g) ----------------
__global__ void k_prep(const float* __restrict__ Wx, const float* __restrict__ bx,
                       const float* __restrict__ Wh, const float* __restrict__ Wc,
                       const float* __restrict__ bh, const float* __restrict__ bc,
                       const int* __restrict__ fix,
                       f16* __restrict__ Wxh, float* __restrict__ bxp,
                       f16* __restrict__ Wbig, f16* __restrict__ Wc2h,
                       float* __restrict__ biasb, int* __restrict__ flag64)
{
  __shared__ int any;
  const int tid = blockIdx.x * blockDim.x + threadIdx.x;
  const int nth = gridDim.x * blockDim.x;
  if (blockIdx.x == 0) {
    if (threadIdx.x == 0) any = 0;
    __syncthreads();
    int a = 0;
    for (int j = 1 + 2 * (int)threadIdx.x; j < B_ * T_; j += 2 * (int)blockDim.x) a |= fix[j];
    if (a) any = 1;
    __syncthreads();
    if (threadIdx.x == 0) flag64[0] = (any == 0) ? 1 : 0;
  }
  for (int i = tid; i < 4 * H_ * INF_; i += nth) {
    const int n = i >> 11, k = i & 2047;
    const int g = n & 3, h = n >> 2;
    Wxh[i] = (f16)Wx[((size_t)(g * H_ + h)) * INF_ + k];
  }
  for (int i = tid; i < NG_ * KC_; i += nth) {
    const int n = i >> 10, k = i & 1023;
    const int g = n & 3, h = n >> 2;
    float v;
    if (k < H_) v = Wh[((size_t)(g * H_ + h)) * H_ + k];
    else {
      const int kk = k - H_;
      v = (g == 0) ? Wc[h * H_ + kk] : (g == 1) ? Wc[H_ * H_ + h * H_ + kk] : 0.0f;
    }
    Wbig[i] = (f16)v;
  }
  for (int i = tid; i < H_ * H_; i += nth) Wc2h[i] = (f16)Wc[2 * H_ * H_ + i];
  for (int i = tid; i < NG_; i += nth) {
    const int g = i & 3, h = i >> 2;
    biasb[i] = bh[g * H_ + h] + ((g == 0) ? bc[h] : (g == 1) ? bc[H_ + h] : 0.0f);
    bxp[i] = bx[g * H_ + h];
  }
}

// ---------------- gather: coalesced row-read, extract 14 columns from LDS ----------------
__global__ __launch_bounds__(256) void k_gather(const float* __restrict__ x,
                                                const int* __restrict__ fix,
                                                const int* __restrict__ flag64,
                                                f16* __restrict__ xg,
                                                int* __restrict__ tlast)
{
  __shared__ float rows[256 * 49];
  __shared__ int wv[T_];
  const int b = blockIdx.x;
  const int tid = threadIdx.x;
  const int is64 = flag64[0];
  if (tid < T_) wv[tid] = is64 ? fix[2 * (b * T_ + tid)] : fix[b * T_ + tid];
  __syncthreads();
  if (blockIdx.y == 0 && tid == 0) {
    int cnt = 0;
    for (int t = 0; t < T_; ++t) cnt += (wv[t] == 0);
    tlast[b] = (cnt < T_) ? (T_ - 1 - cnt) : (T_ - 1);
  }
  const float* xb = x + (size_t)b * (INF_ * HW_);
  for (int c = 0; c < 2; ++c) {
    const int ch = blockIdx.y * 2 + c;
    if (c) __syncthreads();
    const float4* src = (const float4*)(xb + (size_t)ch * 256 * 49);
    float4* dst4 = (float4*)rows;
    for (int i = tid; i < 3136; i += 256) dst4[i] = src[i];
    __syncthreads();
#pragma unroll
    for (int t = 0; t < T_; ++t)
      xg[(size_t)(b * T_ + t) * INF_ + ch * 256 + tid] = (f16)rows[tid * 49 + wv[t]];
  }
}

// ---------------- big GEMM: xproj[3584][2048] = xg @ Wxh^T + bxp ----------------
__global__ __launch_bounds__(256) void k_gemm_big(
    const f16* __restrict__ A, const f16* __restrict__ Bw,
    const float* __restrict__ bxp, float* __restrict__ Cproj)
{
  __shared__ alignas(16) f16 As[128 * 64];
  __shared__ alignas(16) f16 Bs[128 * 64];
  const int tid = threadIdx.x;
  const int lane = tid & 63;
  const int w = tid >> 6;
  const int wm = w >> 1, wn = w & 1;
  const int flat = blockIdx.y * 16 + blockIdx.x;
  const int wg = (flat & 7) * 56 + (flat >> 3);
  const int m0 = (wg >> 4) * 128, n0 = (wg & 15) * 128;
  f32x4 acc[4][4] = {};
  const int lrow = lane >> 3;
  const int kg = lane & 7;
  for (int ks = 0; ks < 2048; ks += 64) {
#pragma unroll
    for (int q = 0; q < 4; ++q) {
      const int chunk = (w << 2) + q;
      const int row = (chunk << 3) + lrow;
      const int skg = kg ^ (row & 7);
      async16(A + (size_t)(m0 + row) * 2048 + ks + (skg << 3), As + chunk * 512);
      async16(Bw + (size_t)(n0 + row) * 2048 + ks + (skg << 3), Bs + chunk * 512);
    }
    __syncthreads();
#pragma unroll
    for (int kk = 0; kk < 2; ++kk) {
      const int kgl = (kk << 2) + (lane >> 4);
      f16x8 af[4], bf[4];
#pragma unroll
      for (int mi = 0; mi < 4; ++mi) {
        const int r = (wm << 6) + (mi << 4) + (lane & 15);
        af[mi] = *(const f16x8*)(As + r * 64 + ((kgl ^ (r & 7)) << 3));
      }
#pragma unroll
      for (int ni = 0; ni < 4; ++ni) {
        const int r = (wn << 6) + (ni << 4) + (lane & 15);
        bf[ni] = *(const f16x8*)(Bs + r * 64 + ((kgl ^ (r & 7)) << 3));
      }
#pragma unroll
      for (int mi = 0; mi < 4; ++mi)
#pragma unroll
        for (int ni = 0; ni < 4; ++ni)
          acc[mi][ni] = __builtin_amdgcn_mfma_f32_16x16x32_f16(af[mi], bf[ni], acc[mi][ni], 0, 0, 0);
    }
    __syncthreads();
  }
#pragma unroll
  for (int mi = 0; mi < 4; ++mi)
#pragma unroll
    for (int ni = 0; ni < 4; ++ni)
#pragma unroll
      for (int r4 = 0; r4 < 4; ++r4) {
        const int row = m0 + (wm << 6) + (mi << 4) + ((lane >> 4) << 2) + r4;
        const int col = n0 + (wn << 6) + (ni << 4) + (lane & 15);
        Cproj[(size_t)row * 2048 + col] = acc[mi][ni][r4] + bxp[col];
      }
}

// ---------------- persistent recurrence: 14 steps, 2 grid barriers/step ----------------
__global__ __launch_bounds__(256) void k_recur(
    const f16* __restrict__ Wbig, const f16* __restrict__ Wc2h,
    const float* __restrict__ biasb, const float* __restrict__ bc,
    const float* __restrict__ xproj, f16* __restrict__ hbuf0,
    f16* __restrict__ hbuf1, float* __restrict__ cbuf,
    float* __restrict__ linO, float* __restrict__ lasth,
    const int* __restrict__ tlast, const float* __restrict__ Wd,
    const float* __restrict__ bd, float* __restrict__ out,
    int* __restrict__ bar)
{
  __shared__ alignas(16) char smem[24576];
  f16* const AsG = (f16*)smem;             // gates A: [2][2048] (8 KB)
  f16* const BsG = (f16*)(smem + 8192);    // gates B: [2][4096] (16 KB)
  f16* const AsO = (f16*)smem;             // outc A: [2][2048]
  f16* const BsO = (f16*)(smem + 8192);    // outc B: [2][2048]
  const int tid = threadIdx.x, lane = tid & 63, w = tid >> 6;
  const int wm = w >> 1, wn = w & 1;
  const int bid = blockIdx.x;
  const int m0A = (bid >> 5) * 32, n0A = (bid & 31) * 64;   // gates: 8 x 32 tiles of 32x64
  const int m0B = (bid >> 4) * 32, n0B = (bid & 15) * 32;   // outc: 8 x 16 tiles of 32x32 (bid<128)

  for (int t = 0; t < T_; ++t) {
    const f16* hr = (t & 1) ? hbuf1 : hbuf0;
    f16* hw = (t & 1) ? hbuf0 : hbuf1;

    // ================= phase A: gates GEMM + c-update =================
    f32x4 acc0 = {}, acc1 = {};
    {
      const int arow = tid >> 3, akg = tid & 7;
      auto stageA = [&](int buf, int ks) {
        async16(hr + (size_t)(m0A + arow) * KC_ + ks + ((akg ^ (arow & 7)) << 3),
                AsG + buf * 2048 + w * 512);
#pragma unroll
        for (int q = 0; q < 2; ++q) {
          const int c = q * 256 + tid;
          const int row = c >> 3, kg = c & 7;
          async16(Wbig + (size_t)(n0A + row) * KC_ + ks + ((kg ^ (row & 7)) << 3),
                  BsG + buf * 4096 + q * 2048 + w * 512);
        }
      };
      stageA(0, 0);
      __syncthreads();
      for (int it = 0; it < 16; ++it) {
        if (it < 15) stageA((it + 1) & 1, (it + 1) * 64);
        const int cb = it & 1;
#pragma unroll
        for (int kk = 0; kk < 2; ++kk) {
          const int kgl = (kk << 2) + (lane >> 4);
          const int ra = wm * 16 + (lane & 15);
          const f16x8 af = *(const f16x8*)(AsG + cb * 2048 + ra * 64 + ((kgl ^ (ra & 7)) << 3));
          const int rb0 = wn * 32 + (lane & 15);
          const f16x8 bf0 = *(const f16x8*)(BsG + cb * 4096 + rb0 * 64 + ((kgl ^ (rb0 & 7)) << 3));
          acc0 = __builtin_amdgcn_mfma_f32_16x16x32_f16(af, bf0, acc0, 0, 0, 0);
          const int rb1 = rb0 + 16;
          const f16x8 bf1 = *(const f16x8*)(BsG + cb * 4096 + rb1 * 64 + ((kgl ^ (rb1 & 7)) << 3));
          acc1 = __builtin_amdgcn_mfma_f32_16x16x32_f16(af, bf1, acc1, 0, 0, 0);
        }
        __syncthreads();
      }
    }
    // epilogue: quad transpose -> each lane holds (i,f,o,m) for one (b,h)
#pragma unroll
    for (int ni = 0; ni < 2; ++ni) {
      const f32x4 a = ni ? acc1 : acc0;
      float a0 = a[0], a1 = a[1], a2 = a[2], a3 = a[3];
      {
        const bool odd = lane & 1;
        float xx = odd ? a0 : a1, yy = odd ? a2 : a3;
        xx = __shfl_xor(xx, 1); yy = __shfl_xor(yy, 1);
        if (odd) { a0 = xx; a2 = yy; } else { a1 = xx; a3 = yy; }
      }
      {
        const bool hi = lane & 2;
        float xx = hi ? a0 : a2, yy = hi ? a1 : a3;
        xx = __shfl_xor(xx, 2); yy = __shfl_xor(yy, 2);
        if (hi) { a0 = xx; a1 = yy; } else { a2 = xx; a3 = yy; }
      }
      const int b = m0A + wm * 16 + ((lane >> 4) << 2) + (lane & 3);
      const int h = ((n0A + wn * 32 + ni * 16) >> 2) + ((lane >> 2) & 3);
      const float4 b4 = *(const float4*)(biasb + 4 * h);
      const float4 x4 = *(const float4*)(xproj + (size_t)(b * T_ + t) * 2048 + 4 * h);
      const float gi = a0 + b4.x + x4.x;
      const float gf = a1 + b4.y + x4.y;
      const float go = a2 + b4.z + x4.z;
      const float gm = a3 + b4.w + x4.w;
      const float cn = sigm(gi) * tanhf(gm) + sigm(gf) * cbuf[b * 512 + h];
      cbuf[b * 512 + h] = cn;
      hw[b * 1024 + 512 + h] = (f16)cn;
      linO[b * 512 + h] = go;
    }
    gbar(bar, 2 * t, bid);

    // ================= phase B: o-peephole GEMM + h write =================
    if (bid < 128) {
      f32x4 acc = {};
      const int row = tid >> 3, kg = tid & 7;
      auto stageB = [&](int buf, int ks) {
        async16(hw + (size_t)(m0B + row) * 1024 + 512 + ks + ((kg ^ (row & 7)) << 3),
                AsO + buf * 2048 + w * 512);
        async16(Wc2h + (size_t)(n0B + row) * 512 + ks + ((kg ^ (row & 7)) << 3),
                BsO + buf * 2048 + w * 512);
      };
      stageB(0, 0);
      __syncthreads();
      for (int it = 0; it < 8; ++it) {
        if (it < 7) stageB((it + 1) & 1, (it + 1) * 64);
        const int cb = it & 1;
#pragma unroll
        for (int kk = 0; kk < 2; ++kk) {
          const int kgl = (kk << 2) + (lane >> 4);
          const int ra = wm * 16 + (lane & 15);
          const int rb = wn * 16 + (lane & 15);
          const f16x8 af = *(const f16x8*)(AsO + cb * 2048 + ra * 64 + ((kgl ^ (ra & 7)) << 3));
          const f16x8 bf = *(const f16x8*)(BsO + cb * 2048 + rb * 64 + ((kgl ^ (rb & 7)) << 3));
          acc = __builtin_amdgcn_mfma_f32_16x16x32_f16(af, bf, acc, 0, 0, 0);
        }
        __syncthreads();
      }
#pragma unroll
      for (int r4 = 0; r4 < 4; ++r4) {
        const int b = m0B + wm * 16 + ((lane >> 4) << 2) + r4;
        const int col = n0B + wn * 16 + (lane & 15);
        const float olin = acc[r4] + linO[b * 512 + col] + bc[1024 + col];
        const float hv = sigm(olin) * cbuf[b * 512 + col];
        hw[(size_t)b * 1024 + col] = (f16)hv;
        if (t == tlast[b]) lasth[b * 512 + col] = hv;
      }
    }
    gbar(bar, 2 * t + 1, bid);
  }

  // ================= final: out[b] = sigmoid(lasth . Wd + bd) =================
  if (bid < 64) {
    const int b = (bid << 2) + w;
    float s = 0.f;
    for (int k = lane; k < 512; k += 64) s += lasth[b * 512 + k] * Wd[k];
#pragma unroll
    for (int off = 32; off > 0; off >>= 1) s += __shfl_down(s, off);
    if (lane == 0) out[b] = 1.0f / (1.0f + __expf(-(s + bd[0])));
  }
}

extern "C" void kernel_launch(void* const* d_in, const int* in_sizes, int n_in,
                              void* d_out, int out_size, void* d_ws, size_t ws_size,
                              hipStream_t stream) {
  const float* x   = (const float*)d_in[0];
  const int*   fix = (const int*)d_in[1];
  const float* Wx  = (const float*)d_in[2];
  const float* bx  = (const float*)d_in[3];
  const float* Wh  = (const float*)d_in[4];
  const float* bh  = (const float*)d_in[5];
  const float* Wc  = (const float*)d_in[6];
  const float* bc  = (const float*)d_in[7];
  const float* Wd  = (const float*)d_in[8];
  const float* bd  = (const float*)d_in[9];
  float* out = (float*)d_out;
  char* ws = (char*)d_ws;

  f16*   xg    = (f16*)(ws);                       // 14,680,064 B
  f16*   Wxh   = (f16*)(ws + 14680064);            //  8,388,608
  float* xproj = (float*)(ws + 23068672);          // 29,360,128
  f16*   Wbig  = (f16*)(ws + 52428800);            //  4,194,304
  f16*   Wc2h  = (f16*)(ws + 56623104);            //    524,288
  float* biasb = (float*)(ws + 57147392);          //      8,192
  float* bxp   = (float*)(ws + 57155584);          //      8,192
  f16*   hbuf0 = (f16*)(ws + 57163776);            //    524,288
  f16*   hbuf1 = (f16*)(ws + 57688064);            //    524,288
  float* cbuf  = (float*)(ws + 58212352);          //    524,288
  float* linO  = (float*)(ws + 58736640);          //    524,288
  float* lasth = (float*)(ws + 59260928);          //    524,288
  int*   tlast = (int*)(ws + 59785216);            //      1,024
  int*   flag64= (int*)(ws + 59786240);            //         64
  int*   bar   = (int*)(ws + 59786304);            //      4,096

  hipMemsetAsync(hbuf0, 0, 524288, stream);
  hipMemsetAsync(cbuf, 0, 524288, stream);
  hipMemsetAsync(bar, 0, 4096, stream);

  k_prep<<<2048, 256, 0, stream>>>(Wx, bx, Wh, Wc, bh, bc, fix, Wxh, bxp, Wbig, Wc2h, biasb, flag64);
  k_gather<<<dim3(256, 4), 256, 0, stream>>>(x, fix, flag64, xg, tlast);
  k_gemm_big<<<dim3(16, 28), 256, 0, stream>>>(xg, Wxh, bxp, xproj);
  k_recur<<<NBLK, 256, 0, stream>>>(Wbig, Wc2h, biasb, bc, xproj, hbuf0, hbuf1,
                                    cbuf, linO, lasth, tlast, Wd, bd, out, bar);
}

// Round 4
// 374.575 us; speedup vs baseline: 3.7547x; 2.9972x over previous
//
#include <hip/hip_runtime.h>
#include <cstdint>
#include <cstddef>

#define B_   256
#define T_   14
#define INF_ 2048
#define H_   512
#define HW_  49
#define NG_  2048   /* 4*H */
#define KC_  1024   /* H (h) + H (c) */
#define NBLK 256

typedef __attribute__((ext_vector_type(8))) _Float16 f16x8;
typedef __attribute__((ext_vector_type(4))) float f32x4;
typedef _Float16 f16;

typedef const void __attribute__((address_space(1))) gvoid_t;
typedef void __attribute__((address_space(3))) svoid_t;

__device__ __forceinline__ void async16(const void* g, void* l) {
  __builtin_amdgcn_global_load_lds((gvoid_t*)g, (svoid_t*)l, 16, 0, 0);
}

__device__ __forceinline__ float sigm(float x) { return 1.0f / (1.0f + __expf(-x)); }

// relaxed agent-scope (sc-flagged) accessors: per-access coherence, NO cache-wide inv
__device__ __forceinline__ float aload(const float* p) {
  return __hip_atomic_load(p, __ATOMIC_RELAXED, __HIP_MEMORY_SCOPE_AGENT);
}
__device__ __forceinline__ unsigned long long aload64(const float* p) {
  return __hip_atomic_load((const unsigned long long*)p, __ATOMIC_RELAXED, __HIP_MEMORY_SCOPE_AGENT);
}
__device__ __forceinline__ void astore(float* p, float v) {
  __hip_atomic_store(p, v, __ATOMIC_RELAXED, __HIP_MEMORY_SCOPE_AGENT);
}
__device__ __forceinline__ void astore64(float* p, unsigned long long v) {
  __hip_atomic_store((unsigned long long*)p, v, __ATOMIC_RELAXED, __HIP_MEMORY_SCOPE_AGENT);
}
__device__ __forceinline__ unsigned long long packf2(float x, float y) {
  return (unsigned long long)__float_as_uint(x) | ((unsigned long long)__float_as_uint(y) << 32);
}

// two-level grid barrier, ALL relaxed (no fences, no buffer_inv).
// visibility: sc-flagged data stores drained by the __syncthreads (vmcnt0) before arrival.
__device__ __forceinline__ void gbar(int* __restrict__ bar, const int p, const int bid) {
  __syncthreads();
  if (threadIdx.x == 0) {
    asm volatile("s_waitcnt vmcnt(0)" ::: "memory");
    int* leaf = bar + ((bid & 15) << 5);
    int* root = bar + 512;
    int* gen  = bar + 544;
    bool release = false;
    if (__hip_atomic_fetch_add(leaf, 1, __ATOMIC_RELAXED, __HIP_MEMORY_SCOPE_AGENT) == (p << 4) + 15) {
      if (__hip_atomic_fetch_add(root, 1, __ATOMIC_RELAXED, __HIP_MEMORY_SCOPE_AGENT) == (p << 4) + 15) {
        __hip_atomic_store(gen, p + 1, __ATOMIC_RELAXED, __HIP_MEMORY_SCOPE_AGENT);
        release = true;
      }
    }
    if (!release) {
      while (__hip_atomic_load(gen, __ATOMIC_RELAXED, __HIP_MEMORY_SCOPE_AGENT) <= p)
        __builtin_amdgcn_s_sleep(2);
    }
  }
  __syncthreads();
}

// ---------------- prep: weight conversions (gate-interleaved n = h*4+g) ----------------
__global__ void k_prep(const float* __restrict__ Wx, const float* __restrict__ bx,
                       const float* __restrict__ Wh, const float* __restrict__ Wc,
                       const float* __restrict__ bh, const float* __restrict__ bc,
                       const int* __restrict__ fix,
                       f16* __restrict__ Wxh, float* __restrict__ bxp,
                       f16* __restrict__ Wbig, f16* __restrict__ Wc2h,
                       float* __restrict__ biasb, int* __restrict__ flag64)
{
  __shared__ int any;
  const int tid = blockIdx.x * blockDim.x + threadIdx.x;
  const int nth = gridDim.x * blockDim.x;
  if (blockIdx.x == 0) {
    if (threadIdx.x == 0) any = 0;
    __syncthreads();
    int a = 0;
    for (int j = 1 + 2 * (int)threadIdx.x; j < B_ * T_; j += 2 * (int)blockDim.x) a |= fix[j];
    if (a) any = 1;
    __syncthreads();
    if (threadIdx.x == 0) flag64[0] = (any == 0) ? 1 : 0;
  }
  for (int i = tid; i < 4 * H_ * INF_; i += nth) {
    const int n = i >> 11, k = i & 2047;
    const int g = n & 3, h = n >> 2;
    Wxh[i] = (f16)Wx[((size_t)(g * H_ + h)) * INF_ + k];
  }
  for (int i = tid; i < NG_ * KC_; i += nth) {
    const int n = i >> 10, k = i & 1023;
    const int g = n & 3, h = n >> 2;
    float v;
    if (k < H_) v = Wh[((size_t)(g * H_ + h)) * H_ + k];
    else {
      const int kk = k - H_;
      v = (g == 0) ? Wc[h * H_ + kk] : (g == 1) ? Wc[H_ * H_ + h * H_ + kk] : 0.0f;
    }
    Wbig[i] = (f16)v;
  }
  for (int i = tid; i < H_ * H_; i += nth) Wc2h[i] = (f16)Wc[2 * H_ * H_ + i];
  for (int i = tid; i < NG_; i += nth) {
    const int g = i & 3, h = i >> 2;
    biasb[i] = bh[g * H_ + h] + ((g == 0) ? bc[h] : (g == 1) ? bc[H_ + h] : 0.0f);
    bxp[i] = bx[g * H_ + h];
  }
}

// ---------------- gather: coalesced row-read, extract 14 columns from LDS ----------------
__global__ __launch_bounds__(256) void k_gather(const float* __restrict__ x,
                                                const int* __restrict__ fix,
                                                const int* __restrict__ flag64,
                                                f16* __restrict__ xg,
                                                int* __restrict__ tlast)
{
  __shared__ float rows[256 * 49];
  __shared__ int wv[T_];
  const int b = blockIdx.x;
  const int tid = threadIdx.x;
  const int is64 = flag64[0];
  if (tid < T_) wv[tid] = is64 ? fix[2 * (b * T_ + tid)] : fix[b * T_ + tid];
  __syncthreads();
  if (blockIdx.y == 0 && tid == 0) {
    int cnt = 0;
    for (int t = 0; t < T_; ++t) cnt += (wv[t] == 0);
    tlast[b] = (cnt < T_) ? (T_ - 1 - cnt) : (T_ - 1);
  }
  const float* xb = x + (size_t)b * (INF_ * HW_);
  for (int c = 0; c < 2; ++c) {
    const int ch = blockIdx.y * 2 + c;
    if (c) __syncthreads();
    const float4* src = (const float4*)(xb + (size_t)ch * 256 * 49);
    float4* dst4 = (float4*)rows;
    for (int i = tid; i < 3136; i += 256) dst4[i] = src[i];
    __syncthreads();
#pragma unroll
    for (int t = 0; t < T_; ++t)
      xg[(size_t)(b * T_ + t) * INF_ + ch * 256 + tid] = (f16)rows[tid * 49 + wv[t]];
  }
}

// ---------------- big GEMM: xproj[3584][2048] = xg @ Wxh^T + bxp ----------------
__global__ __launch_bounds__(256) void k_gemm_big(
    const f16* __restrict__ A, const f16* __restrict__ Bw,
    const float* __restrict__ bxp, float* __restrict__ Cproj)
{
  __shared__ alignas(16) f16 As[128 * 64];
  __shared__ alignas(16) f16 Bs[128 * 64];
  const int tid = threadIdx.x;
  const int lane = tid & 63;
  const int w = tid >> 6;
  const int wm = w >> 1, wn = w & 1;
  const int flat = blockIdx.y * 16 + blockIdx.x;
  const int wg = (flat & 7) * 56 + (flat >> 3);
  const int m0 = (wg >> 4) * 128, n0 = (wg & 15) * 128;
  f32x4 acc[4][4] = {};
  const int lrow = lane >> 3;
  const int kg = lane & 7;
  for (int ks = 0; ks < 2048; ks += 64) {
#pragma unroll
    for (int q = 0; q < 4; ++q) {
      const int chunk = (w << 2) + q;
      const int row = (chunk << 3) + lrow;
      const int skg = kg ^ (row & 7);
      async16(A + (size_t)(m0 + row) * 2048 + ks + (skg << 3), As + chunk * 512);
      async16(Bw + (size_t)(n0 + row) * 2048 + ks + (skg << 3), Bs + chunk * 512);
    }
    __syncthreads();
#pragma unroll
    for (int kk = 0; kk < 2; ++kk) {
      const int kgl = (kk << 2) + (lane >> 4);
      f16x8 af[4], bf[4];
#pragma unroll
      for (int mi = 0; mi < 4; ++mi) {
        const int r = (wm << 6) + (mi << 4) + (lane & 15);
        af[mi] = *(const f16x8*)(As + r * 64 + ((kgl ^ (r & 7)) << 3));
      }
#pragma unroll
      for (int ni = 0; ni < 4; ++ni) {
        const int r = (wn << 6) + (ni << 4) + (lane & 15);
        bf[ni] = *(const f16x8*)(Bs + r * 64 + ((kgl ^ (r & 7)) << 3));
      }
#pragma unroll
      for (int mi = 0; mi < 4; ++mi)
#pragma unroll
        for (int ni = 0; ni < 4; ++ni)
          acc[mi][ni] = __builtin_amdgcn_mfma_f32_16x16x32_f16(af[mi], bf[ni], acc[mi][ni], 0, 0, 0);
    }
    __syncthreads();
  }
#pragma unroll
  for (int mi = 0; mi < 4; ++mi)
#pragma unroll
    for (int ni = 0; ni < 4; ++ni)
#pragma unroll
      for (int r4 = 0; r4 < 4; ++r4) {
        const int row = m0 + (wm << 6) + (mi << 4) + ((lane >> 4) << 2) + r4;
        const int col = n0 + (wn << 6) + (ni << 4) + (lane & 15);
        Cproj[(size_t)row * 2048 + col] = acc[mi][ni][r4] + bxp[col];
      }
}

// ---------------- persistent recurrence: coherent state, register-resident c ----------------
__global__ __launch_bounds__(256) void k_recur(
    const f16* __restrict__ Wbig, const f16* __restrict__ Wc2h,
    const float* __restrict__ biasb, const float* __restrict__ bc,
    const float* __restrict__ xproj, float* __restrict__ hbuf,
    float* __restrict__ cbuf, float* __restrict__ linO,
    float* __restrict__ lasth, const int* __restrict__ tlast,
    const float* __restrict__ Wd, const float* __restrict__ bd,
    float* __restrict__ out, int* __restrict__ bar)
{
  __shared__ alignas(16) char smem[81920];
  f16* const Atile = (f16*)smem;           // A: [32][1024] f16 (A-phase) / [32][512] (B-phase)
  f16* const Bst   = (f16*)(smem + 65536); // B dbuf: 2x4096 f16 (A) / 2x2048 (B); exch reuse
  const int tid = threadIdx.x, lane = tid & 63, w = tid >> 6;
  const int wm = w >> 1, wn = w & 1;
  const int bid = blockIdx.x;
  const int m0A = (bid >> 5) * 32, n0A = (bid & 31) * 64;   // gates: 8m x 32n tiles 32x64
  const int m0B = (bid >> 4) * 32, n0B = (bid & 15) * 32;   // outc:  8m x 16n tiles 32x32 (bid<128)
  float creg[2] = {0.f, 0.f};

  for (int t = 0; t < T_; ++t) {
    // ========== phase A: gates GEMM over [h|c] + c-update ==========
    // stage A tile [32][1024] f16 from hbuf|cbuf (coherent f32 loads)
#pragma unroll
    for (int j = 0; j < 16; ++j) {
      const int u = (j << 8) + tid;
      const int row = u >> 7, kg = u & 127;
      const float* src = (kg < 64) ? (hbuf + (size_t)(m0A + row) * 512 + (kg << 3))
                                   : (cbuf + (size_t)(m0A + row) * 512 + ((kg - 64) << 3));
      f16x8 v;
#pragma unroll
      for (int pz = 0; pz < 4; ++pz) {
        const unsigned long long q = aload64(src + (pz << 1));
        v[2 * pz]     = (f16)__uint_as_float((unsigned)q);
        v[2 * pz + 1] = (f16)__uint_as_float((unsigned)(q >> 32));
      }
      *(f16x8*)(Atile + row * 1024 + ((kg >> 3) << 6) + (((kg & 7) ^ (row & 7)) << 3)) = v;
    }
    auto stageBG = [&](int buf, int ks) {
#pragma unroll
      for (int q = 0; q < 2; ++q) {
        const int c = (q << 8) + tid;
        const int row = c >> 3, kg = c & 7;
        async16(Wbig + (size_t)(n0A + row) * KC_ + ks + ((kg ^ (row & 7)) << 3),
                Bst + buf * 4096 + q * 2048 + w * 512);
      }
    };
    stageBG(0, 0);
    __syncthreads();
    f32x4 acc0 = {}, acc1 = {};
    for (int it = 0; it < 16; ++it) {
      if (it < 15) stageBG((it + 1) & 1, (it + 1) << 6);
      const int cb = it & 1;
#pragma unroll
      for (int kk = 0; kk < 2; ++kk) {
        const int kgl = (kk << 2) + (lane >> 4);
        const int ra = wm * 16 + (lane & 15);
        const f16x8 af = *(const f16x8*)(Atile + ra * 1024 + (it << 6) + ((kgl ^ (ra & 7)) << 3));
        const int rb0 = wn * 32 + (lane & 15);
        const f16x8 bf0 = *(const f16x8*)(Bst + cb * 4096 + rb0 * 64 + ((kgl ^ (rb0 & 7)) << 3));
        acc0 = __builtin_amdgcn_mfma_f32_16x16x32_f16(af, bf0, acc0, 0, 0, 0);
        const int rb1 = rb0 + 16;
        const f16x8 bf1 = *(const f16x8*)(Bst + cb * 4096 + rb1 * 64 + ((kgl ^ (rb1 & 7)) << 3));
        acc1 = __builtin_amdgcn_mfma_f32_16x16x32_f16(af, bf1, acc1, 0, 0, 0);
      }
      __syncthreads();
    }
    // epilogue: quad transpose -> lane holds (i,f,o,m) of one (b,h); c in registers
    float* exch = (float*)Bst;   // [cn 32x16 | go 32x16] f32
#pragma unroll
    for (int ni = 0; ni < 2; ++ni) {
      const f32x4 a = ni ? acc1 : acc0;
      float a0 = a[0], a1 = a[1], a2 = a[2], a3 = a[3];
      {
        const bool odd = lane & 1;
        float xx = odd ? a0 : a1, yy = odd ? a2 : a3;
        xx = __shfl_xor(xx, 1); yy = __shfl_xor(yy, 1);
        if (odd) { a0 = xx; a2 = yy; } else { a1 = xx; a3 = yy; }
      }
      {
        const bool hi = lane & 2;
        float xx = hi ? a0 : a2, yy = hi ? a1 : a3;
        xx = __shfl_xor(xx, 2); yy = __shfl_xor(yy, 2);
        if (hi) { a0 = xx; a1 = yy; } else { a2 = xx; a3 = yy; }
      }
      const int brow = wm * 16 + ((lane >> 4) << 2) + (lane & 3);
      const int hl = wn * 8 + ni * 4 + ((lane >> 2) & 3);
      const int bg = m0A + brow;
      const int hg = (n0A >> 2) + hl;
      const float4 b4 = *(const float4*)(biasb + 4 * hg);
      const float4 x4 = *(const float4*)(xproj + (size_t)(bg * T_ + t) * 2048 + 4 * hg);
      const float gi = a0 + b4.x + x4.x;
      const float gf = a1 + b4.y + x4.y;
      const float go = a2 + b4.z + x4.z;
      const float gm = a3 + b4.w + x4.w;
      const float cn = sigm(gi) * tanhf(gm) + sigm(gf) * creg[ni];
      creg[ni] = cn;
      exch[brow * 16 + hl] = cn;
      exch[512 + brow * 16 + hl] = go;
    }
    __syncthreads();
    {
      const int rowe = tid >> 3, pr = tid & 7;
      const int hb = (n0A >> 2) + (pr << 1);
      const float2 cp = *(const float2*)(exch + rowe * 16 + (pr << 1));
      astore64(cbuf + (size_t)(m0A + rowe) * 512 + hb, packf2(cp.x, cp.y));
      const float2 gp = *(const float2*)(exch + 512 + rowe * 16 + (pr << 1));
      astore64(linO + (size_t)(m0A + rowe) * 512 + hb, packf2(gp.x, gp.y));
    }
    gbar(bar, 2 * t, bid);

    // ========== phase B: o-peephole GEMM + h write ==========
    if (bid < 128) {
#pragma unroll
      for (int j = 0; j < 8; ++j) {
        const int u = (j << 8) + tid;
        const int row = u >> 6, kg = u & 63;
        const float* src = cbuf + (size_t)(m0B + row) * 512 + (kg << 3);
        f16x8 v;
#pragma unroll
        for (int pz = 0; pz < 4; ++pz) {
          const unsigned long long q = aload64(src + (pz << 1));
          v[2 * pz]     = (f16)__uint_as_float((unsigned)q);
          v[2 * pz + 1] = (f16)__uint_as_float((unsigned)(q >> 32));
        }
        *(f16x8*)(Atile + row * 512 + ((kg >> 3) << 6) + (((kg & 7) ^ (row & 7)) << 3)) = v;
      }
      auto stageBO = [&](int buf, int ks) {
        const int row = tid >> 3, kg = tid & 7;
        async16(Wc2h + (size_t)(n0B + row) * H_ + ks + ((kg ^ (row & 7)) << 3),
                Bst + buf * 2048 + w * 512);
      };
      stageBO(0, 0);
      __syncthreads();
      f32x4 acc = {};
      for (int it = 0; it < 8; ++it) {
        if (it < 7) stageBO((it + 1) & 1, (it + 1) << 6);
        const int cb = it & 1;
#pragma unroll
        for (int kk = 0; kk < 2; ++kk) {
          const int kgl = (kk << 2) + (lane >> 4);
          const int ra = wm * 16 + (lane & 15);
          const f16x8 af = *(const f16x8*)(Atile + ra * 512 + (it << 6) + ((kgl ^ (ra & 7)) << 3));
          const int rb = wn * 16 + (lane & 15);
          const f16x8 bf = *(const f16x8*)(Bst + cb * 2048 + rb * 64 + ((kgl ^ (rb & 7)) << 3));
          acc = __builtin_amdgcn_mfma_f32_16x16x32_f16(af, bf, acc, 0, 0, 0);
        }
        __syncthreads();
      }
#pragma unroll
      for (int r4 = 0; r4 < 4; ++r4) {
        const int brow = wm * 16 + ((lane >> 4) << 2) + r4;
        const int b = m0B + brow;
        const int col = n0B + wn * 16 + (lane & 15);
        const float go = aload(linO + (size_t)b * 512 + col);
        const float cn = (float)Atile[brow * 512 + ((col >> 6) << 6) +
                                      ((((col >> 3) & 7) ^ (brow & 7)) << 3) + (col & 7)];
        const float hv = sigm(acc[r4] + go + bc[1024 + col]) * cn;
        astore(hbuf + (size_t)b * 512 + col, hv);
        if (t == tlast[b]) astore(lasth + (size_t)b * 512 + col, hv);
      }
    }
    gbar(bar, 2 * t + 1, bid);
  }

  // ========== final: out[b] = sigmoid(lasth . Wd + bd) ==========
  if (bid < 64) {
    const int b = (bid << 2) + w;
    float s = 0.f;
    for (int k = lane; k < 512; k += 64) s += aload(lasth + (size_t)b * 512 + k) * Wd[k];
#pragma unroll
    for (int off = 32; off > 0; off >>= 1) s += __shfl_down(s, off);
    if (lane == 0) out[b] = 1.0f / (1.0f + __expf(-(s + bd[0])));
  }
}

extern "C" void kernel_launch(void* const* d_in, const int* in_sizes, int n_in,
                              void* d_out, int out_size, void* d_ws, size_t ws_size,
                              hipStream_t stream) {
  const float* x   = (const float*)d_in[0];
  const int*   fix = (const int*)d_in[1];
  const float* Wx  = (const float*)d_in[2];
  const float* bx  = (const float*)d_in[3];
  const float* Wh  = (const float*)d_in[4];
  const float* bh  = (const float*)d_in[5];
  const float* Wc  = (const float*)d_in[6];
  const float* bc  = (const float*)d_in[7];
  const float* Wd  = (const float*)d_in[8];
  const float* bd  = (const float*)d_in[9];
  float* out = (float*)d_out;
  char* ws = (char*)d_ws;

  f16*   xg    = (f16*)(ws);                       // 14,680,064 B
  f16*   Wxh   = (f16*)(ws + 14680064);            //  8,388,608
  float* xproj = (float*)(ws + 23068672);          // 29,360,128
  f16*   Wbig  = (f16*)(ws + 52428800);            //  4,194,304
  f16*   Wc2h  = (f16*)(ws + 56623104);            //    524,288
  float* biasb = (float*)(ws + 57147392);          //      8,192
  float* bxp   = (float*)(ws + 57155584);          //      8,192
  float* hbuf  = (float*)(ws + 57163776);          //    524,288
  float* cbuf  = (float*)(ws + 57688064);          //    524,288
  float* linO  = (float*)(ws + 58212352);          //    524,288
  float* lasth = (float*)(ws + 58736640);          //    524,288
  int*   tlast = (int*)(ws + 59260928);            //      1,024
  int*   flag64= (int*)(ws + 59261952);            //         64
  int*   bar   = (int*)(ws + 59262016);            //      4,096

  hipMemsetAsync(hbuf, 0, 524288, stream);
  hipMemsetAsync(cbuf, 0, 524288, stream);
  hipMemsetAsync(bar, 0, 4096, stream);

  k_prep<<<2048, 256, 0, stream>>>(Wx, bx, Wh, Wc, bh, bc, fix, Wxh, bxp, Wbig, Wc2h, biasb, flag64);
  k_gather<<<dim3(256, 4), 256, 0, stream>>>(x, fix, flag64, xg, tlast);
  k_gemm_big<<<dim3(16, 28), 256, 0, stream>>>(xg, Wxh, bxp, xproj);
  k_recur<<<NBLK, 256, 0, stream>>>(Wbig, Wc2h, biasb, bc, xproj, hbuf, cbuf,
                                    linO, lasth, tlast, Wd, bd, out, bar);
}

// Round 5
// 290.125 us; speedup vs baseline: 4.8476x; 1.2911x over previous
//
#include <hip/hip_runtime.h>
#include <cstdint>
#include <cstddef>

#define B_   256
#define T_   14
#define INF_ 2048
#define H_   512
#define HW_  49
#define NG_  2048   /* 4*H */
#define KC_  1024   /* H (h) + H (c) */
#define NBLK 256

typedef __attribute__((ext_vector_type(8))) _Float16 f16x8;
typedef __attribute__((ext_vector_type(4))) float f32x4;
typedef _Float16 f16;

typedef const void __attribute__((address_space(1))) gvoid_t;
typedef void __attribute__((address_space(3))) svoid_t;

__device__ __forceinline__ void async16(const void* g, void* l) {
  __builtin_amdgcn_global_load_lds((gvoid_t*)g, (svoid_t*)l, 16, 0, 0);
}

__device__ __forceinline__ float sigm(float x) { return 1.0f / (1.0f + __expf(-x)); }

// relaxed agent-scope accessors: per-access coherence, NO cache-wide inv
__device__ __forceinline__ float aload(const float* p) {
  return __hip_atomic_load(p, __ATOMIC_RELAXED, __HIP_MEMORY_SCOPE_AGENT);
}
__device__ __forceinline__ unsigned long long aload64(const void* p) {
  return __hip_atomic_load((const unsigned long long*)p, __ATOMIC_RELAXED, __HIP_MEMORY_SCOPE_AGENT);
}
__device__ __forceinline__ void astore(float* p, float v) {
  __hip_atomic_store(p, v, __ATOMIC_RELAXED, __HIP_MEMORY_SCOPE_AGENT);
}
__device__ __forceinline__ void astore32(void* p, unsigned v) {
  __hip_atomic_store((unsigned*)p, v, __ATOMIC_RELAXED, __HIP_MEMORY_SCOPE_AGENT);
}
__device__ __forceinline__ void astore64(void* p, unsigned long long v) {
  __hip_atomic_store((unsigned long long*)p, v, __ATOMIC_RELAXED, __HIP_MEMORY_SCOPE_AGENT);
}
__device__ __forceinline__ unsigned long long packf2(float x, float y) {
  return (unsigned long long)__float_as_uint(x) | ((unsigned long long)__float_as_uint(y) << 32);
}

// two-level grid barrier, all relaxed; data visibility via vmcnt(0) drain before arrival
__device__ __forceinline__ void gbar(int* __restrict__ bar, const int p, const int bid) {
  __syncthreads();
  if (threadIdx.x == 0) {
    asm volatile("s_waitcnt vmcnt(0)" ::: "memory");
    int* leaf = bar + ((bid & 15) << 5);
    int* root = bar + 512;
    int* gen  = bar + 544;
    bool release = false;
    if (__hip_atomic_fetch_add(leaf, 1, __ATOMIC_RELAXED, __HIP_MEMORY_SCOPE_AGENT) == (p << 4) + 15) {
      if (__hip_atomic_fetch_add(root, 1, __ATOMIC_RELAXED, __HIP_MEMORY_SCOPE_AGENT) == (p << 4) + 15) {
        __hip_atomic_store(gen, p + 1, __ATOMIC_RELAXED, __HIP_MEMORY_SCOPE_AGENT);
        release = true;
      }
    }
    if (!release) {
      while (__hip_atomic_load(gen, __ATOMIC_RELAXED, __HIP_MEMORY_SCOPE_AGENT) <= p)
        __builtin_amdgcn_s_sleep(1);
    }
  }
  __syncthreads();
}

// ---------------- prep: weight conversions (gate-interleaved n = h*4+g) ----------------
__global__ void k_prep(const float* __restrict__ Wx, const float* __restrict__ bx,
                       const float* __restrict__ Wh, const float* __restrict__ Wc,
                       const float* __restrict__ bh, const float* __restrict__ bc,
                       const int* __restrict__ fix,
                       f16* __restrict__ Wxh, float* __restrict__ bxp,
                       f16* __restrict__ Wbig, f16* __restrict__ Wc2h,
                       float* __restrict__ biasb, int* __restrict__ flag64)
{
  __shared__ int any;
  const int tid = blockIdx.x * blockDim.x + threadIdx.x;
  const int nth = gridDim.x * blockDim.x;
  if (blockIdx.x == 0) {
    if (threadIdx.x == 0) any = 0;
    __syncthreads();
    int a = 0;
    for (int j = 1 + 2 * (int)threadIdx.x; j < B_ * T_; j += 2 * (int)blockDim.x) a |= fix[j];
    if (a) any = 1;
    __syncthreads();
    if (threadIdx.x == 0) flag64[0] = (any == 0) ? 1 : 0;
  }
  for (int i = tid; i < 4 * H_ * INF_; i += nth) {
    const int n = i >> 11, k = i & 2047;
    const int g = n & 3, h = n >> 2;
    Wxh[i] = (f16)Wx[((size_t)(g * H_ + h)) * INF_ + k];
  }
  for (int i = tid; i < NG_ * KC_; i += nth) {
    const int n = i >> 10, k = i & 1023;
    const int g = n & 3, h = n >> 2;
    float v;
    if (k < H_) v = Wh[((size_t)(g * H_ + h)) * H_ + k];
    else {
      const int kk = k - H_;
      v = (g == 0) ? Wc[h * H_ + kk] : (g == 1) ? Wc[H_ * H_ + h * H_ + kk] : 0.0f;
    }
    Wbig[i] = (f16)v;
  }
  for (int i = tid; i < H_ * H_; i += nth) Wc2h[i] = (f16)Wc[2 * H_ * H_ + i];
  for (int i = tid; i < NG_; i += nth) {
    const int g = i & 3, h = i >> 2;
    biasb[i] = bh[g * H_ + h] + ((g == 0) ? bc[h] : (g == 1) ? bc[H_ + h] : 0.0f);
    bxp[i] = bx[g * H_ + h];
  }
}

// ---------------- gather: coalesced row-read, extract 14 columns from LDS ----------------
__global__ __launch_bounds__(256) void k_gather(const float* __restrict__ x,
                                                const int* __restrict__ fix,
                                                const int* __restrict__ flag64,
                                                f16* __restrict__ xg,
                                                int* __restrict__ tlast)
{
  __shared__ float rows[256 * 49];
  __shared__ int wv[T_];
  const int b = blockIdx.x;
  const int tid = threadIdx.x;
  const int is64 = flag64[0];
  if (tid < T_) wv[tid] = is64 ? fix[2 * (b * T_ + tid)] : fix[b * T_ + tid];
  __syncthreads();
  if (blockIdx.y == 0 && tid == 0) {
    int cnt = 0;
    for (int t = 0; t < T_; ++t) cnt += (wv[t] == 0);
    tlast[b] = (cnt < T_) ? (T_ - 1 - cnt) : (T_ - 1);
  }
  const float* xb = x + (size_t)b * (INF_ * HW_);
  for (int c = 0; c < 2; ++c) {
    const int ch = blockIdx.y * 2 + c;
    if (c) __syncthreads();
    const float4* src = (const float4*)(xb + (size_t)ch * 256 * 49);
    float4* dst4 = (float4*)rows;
    for (int i = tid; i < 3136; i += 256) dst4[i] = src[i];
    __syncthreads();
#pragma unroll
    for (int t = 0; t < T_; ++t)
      xg[(size_t)(b * T_ + t) * INF_ + ch * 256 + tid] = (f16)rows[tid * 49 + wv[t]];
  }
}

// ---------------- big GEMM: xproj[3584][2048] = xg @ Wxh^T + bxp ----------------
__global__ __launch_bounds__(256) void k_gemm_big(
    const f16* __restrict__ A, const f16* __restrict__ Bw,
    const float* __restrict__ bxp, float* __restrict__ Cproj)
{
  __shared__ alignas(16) f16 As[128 * 64];
  __shared__ alignas(16) f16 Bs[128 * 64];
  const int tid = threadIdx.x;
  const int lane = tid & 63;
  const int w = tid >> 6;
  const int wm = w >> 1, wn = w & 1;
  const int flat = blockIdx.y * 16 + blockIdx.x;
  const int wg = (flat & 7) * 56 + (flat >> 3);
  const int m0 = (wg >> 4) * 128, n0 = (wg & 15) * 128;
  f32x4 acc[4][4] = {};
  const int lrow = lane >> 3;
  const int kg = lane & 7;
  for (int ks = 0; ks < 2048; ks += 64) {
#pragma unroll
    for (int q = 0; q < 4; ++q) {
      const int chunk = (w << 2) + q;
      const int row = (chunk << 3) + lrow;
      const int skg = kg ^ (row & 7);
      async16(A + (size_t)(m0 + row) * 2048 + ks + (skg << 3), As + chunk * 512);
      async16(Bw + (size_t)(n0 + row) * 2048 + ks + (skg << 3), Bs + chunk * 512);
    }
    __syncthreads();
#pragma unroll
    for (int kk = 0; kk < 2; ++kk) {
      const int kgl = (kk << 2) + (lane >> 4);
      f16x8 af[4], bf[4];
#pragma unroll
      for (int mi = 0; mi < 4; ++mi) {
        const int r = (wm << 6) + (mi << 4) + (lane & 15);
        af[mi] = *(const f16x8*)(As + r * 64 + ((kgl ^ (r & 7)) << 3));
      }
#pragma unroll
      for (int ni = 0; ni < 4; ++ni) {
        const int r = (wn << 6) + (ni << 4) + (lane & 15);
        bf[ni] = *(const f16x8*)(Bs + r * 64 + ((kgl ^ (r & 7)) << 3));
      }
#pragma unroll
      for (int mi = 0; mi < 4; ++mi)
#pragma unroll
        for (int ni = 0; ni < 4; ++ni)
          acc[mi][ni] = __builtin_amdgcn_mfma_f32_16x16x32_f16(af[mi], bf[ni], acc[mi][ni], 0, 0, 0);
    }
    __syncthreads();
  }
#pragma unroll
  for (int mi = 0; mi < 4; ++mi)
#pragma unroll
    for (int ni = 0; ni < 4; ++ni)
#pragma unroll
      for (int r4 = 0; r4 < 4; ++r4) {
        const int row = m0 + (wm << 6) + (mi << 4) + ((lane >> 4) << 2) + r4;
        const int col = n0 + (wn << 6) + (ni << 4) + (lane & 15);
        Cproj[(size_t)row * 2048 + col] = acc[mi][ni][r4] + bxp[col];
      }
}

// ---------------- persistent recurrence: register-resident weights ----------------
__global__ __launch_bounds__(256, 1) void k_recur(
    const f16* __restrict__ Wbig, const f16* __restrict__ Wc2h,
    const float* __restrict__ biasb, const float* __restrict__ bc,
    const float* __restrict__ xproj, f16* __restrict__ h16,
    f16* __restrict__ cb16, float* __restrict__ linO,
    float* __restrict__ lasth, const int* __restrict__ tlast,
    const float* __restrict__ Wd, const float* __restrict__ bd,
    float* __restrict__ out, int* __restrict__ bar)
{
  __shared__ alignas(16) f16 Atile[32 * 1024];   // 64 KB; reused as cn-tile / exch
  const int tid = threadIdx.x, lane = tid & 63, w = tid >> 6;
  const int wm = w >> 1, wn = w & 1;
  const int lk = lane >> 4;
  const int bid = blockIdx.x;
  const int m0A = (bid >> 5) * 32, n0A = (bid & 31) * 64;   // gates: 8m x 32n, tile 32x64
  const int m0B = (bid >> 4) * 32, n0B = (bid & 15) * 32;   // outc : 8m x 16n, tile 32x32 (bid<128)

  // ---- resident weights ----
  f16x8 wG[2][32];
#pragma unroll
  for (int ni = 0; ni < 2; ++ni) {
    const f16* src = Wbig + (size_t)(n0A + wn * 32 + ni * 16 + (lane & 15)) * 1024 + (lk << 3);
#pragma unroll
    for (int kc = 0; kc < 32; ++kc) wG[ni][kc] = *(const f16x8*)(src + kc * 32);
  }
  f16x8 wO[16];
  float bco = 0.f;
  int tl4[4];
  if (bid < 128) {
    const f16* src = Wc2h + (size_t)(n0B + wn * 16 + (lane & 15)) * 512 + (lk << 3);
#pragma unroll
    for (int kc = 0; kc < 16; ++kc) wO[kc] = *(const f16x8*)(src + kc * 32);
    bco = bc[1024 + n0B + wn * 16 + (lane & 15)];
#pragma unroll
    for (int r4 = 0; r4 < 4; ++r4) tl4[r4] = tlast[m0B + wm * 16 + (lk << 2) + r4];
  }
  // hoisted epilogue constants (phase A)
  const int browA = wm * 16 + (lk << 2) + (lane & 3);
  const int bgA = m0A + browA;
  float4 b4c[2];
#pragma unroll
  for (int ni = 0; ni < 2; ++ni)
    b4c[ni] = *(const float4*)(biasb + 4 * ((n0A >> 2) + wn * 8 + ni * 4 + ((lane >> 2) & 3)));

  float creg[2] = {0.f, 0.f};

  for (int t = 0; t < T_; ++t) {
    // ========== phase A: gates GEMM over [h|c] ==========
    // prefetch xproj for epilogue (cached loads, in flight across stage+MFMA)
    float4 x4p[2];
#pragma unroll
    for (int ni = 0; ni < 2; ++ni)
      x4p[ni] = *(const float4*)(xproj + (size_t)(bgA * T_ + t) * 2048 +
                                 4 * ((n0A >> 2) + wn * 8 + ni * 4 + ((lane >> 2) & 3)));
    // stage A-tile [32][1024] f16 from h16|cb16 (coherent, 32 aload64/thread)
#pragma unroll
    for (int j = 0; j < 16; ++j) {
      const int u = (j << 8) + tid;
      const int row = u >> 7, kg = u & 127;
      const f16* src = (kg < 64) ? (h16 + (size_t)(m0A + row) * 512 + (kg << 3))
                                 : (cb16 + (size_t)(m0A + row) * 512 + ((kg - 64) << 3));
      union { f16x8 v; unsigned long long q[2]; } u2;
      u2.q[0] = aload64(src);
      u2.q[1] = aload64(src + 4);
      *(f16x8*)(Atile + row * 1024 + ((kg >> 3) << 6) + (((kg & 7) ^ (row & 7)) << 3)) = u2.v;
    }
    __syncthreads();
    {
      f32x4 acc[2][2] = {};
      const int ra = wm * 16 + (lane & 15);
      const f16* arow = Atile + ra * 1024;
#pragma unroll
      for (int kc = 0; kc < 32; ++kc) {
        const int kgl = ((kc & 1) << 2) + lk;
        const f16x8 af = *(const f16x8*)(arow + ((kc >> 1) << 6) + ((kgl ^ (ra & 7)) << 3));
        acc[kc & 1][0] = __builtin_amdgcn_mfma_f32_16x16x32_f16(af, wG[0][kc], acc[kc & 1][0], 0, 0, 0);
        acc[kc & 1][1] = __builtin_amdgcn_mfma_f32_16x16x32_f16(af, wG[1][kc], acc[kc & 1][1], 0, 0, 0);
      }
      __syncthreads();   // done reading Atile; reuse as exch
      float* exch = (float*)Atile;
#pragma unroll
      for (int ni = 0; ni < 2; ++ni) {
        const f32x4 a = acc[0][ni] + acc[1][ni];
        float a0 = a[0], a1 = a[1], a2 = a[2], a3 = a[3];
        {
          const bool odd = lane & 1;
          float xx = odd ? a0 : a1, yy = odd ? a2 : a3;
          xx = __shfl_xor(xx, 1); yy = __shfl_xor(yy, 1);
          if (odd) { a0 = xx; a2 = yy; } else { a1 = xx; a3 = yy; }
        }
        {
          const bool hi = lane & 2;
          float xx = hi ? a0 : a2, yy = hi ? a1 : a3;
          xx = __shfl_xor(xx, 2); yy = __shfl_xor(yy, 2);
          if (hi) { a0 = xx; a1 = yy; } else { a2 = xx; a3 = yy; }
        }
        const int hl = wn * 8 + ni * 4 + ((lane >> 2) & 3);
        const float gi = a0 + b4c[ni].x + x4p[ni].x;
        const float gf = a1 + b4c[ni].y + x4p[ni].y;
        const float go = a2 + b4c[ni].z + x4p[ni].z;
        const float gm = a3 + b4c[ni].w + x4p[ni].w;
        const float cn = sigm(gi) * tanhf(gm) + sigm(gf) * creg[ni];
        creg[ni] = cn;
        exch[browA * 16 + hl] = cn;
        exch[512 + browA * 16 + hl] = go;
      }
      __syncthreads();
      {
        const int rowe = tid >> 3, pr = tid & 7;
        const int hb = (n0A >> 2) + (pr << 1);
        const float2 cp = *(const float2*)(exch + rowe * 16 + (pr << 1));
        union { unsigned u; f16 h[2]; } pk;
        pk.h[0] = (f16)cp.x; pk.h[1] = (f16)cp.y;
        astore32(cb16 + (size_t)(m0A + rowe) * 512 + hb, pk.u);
        const float2 gp = *(const float2*)(exch + 512 + rowe * 16 + (pr << 1));
        astore64(linO + (size_t)(m0A + rowe) * 512 + hb, packf2(gp.x, gp.y));
      }
    }
    gbar(bar, 2 * t, bid);

    // ========== phase B: o-peephole GEMM + h write ==========
    if (bid < 128) {
      // prefetch linO (coherent) for epilogue
      float go4[4];
#pragma unroll
      for (int r4 = 0; r4 < 4; ++r4)
        go4[r4] = aload(linO + (size_t)(m0B + wm * 16 + (lk << 2) + r4) * 512 + n0B + wn * 16 + (lane & 15));
      // stage cn-tile [32][512] f16 from cb16
#pragma unroll
      for (int j = 0; j < 8; ++j) {
        const int u = (j << 8) + tid;
        const int row = u >> 6, kg = u & 63;
        const f16* src = cb16 + (size_t)(m0B + row) * 512 + (kg << 3);
        union { f16x8 v; unsigned long long q[2]; } u2;
        u2.q[0] = aload64(src);
        u2.q[1] = aload64(src + 4);
        *(f16x8*)(Atile + row * 512 + ((kg >> 3) << 6) + (((kg & 7) ^ (row & 7)) << 3)) = u2.v;
      }
      __syncthreads();
      f32x4 accB[2] = {};
      const int ra = wm * 16 + (lane & 15);
      const f16* arow = Atile + ra * 512;
#pragma unroll
      for (int kc = 0; kc < 16; ++kc) {
        const int kgl = ((kc & 1) << 2) + lk;
        const f16x8 af = *(const f16x8*)(arow + ((kc >> 1) << 6) + ((kgl ^ (ra & 7)) << 3));
        accB[kc & 1] = __builtin_amdgcn_mfma_f32_16x16x32_f16(af, wO[kc], accB[kc & 1], 0, 0, 0);
      }
      const f32x4 aB = accB[0] + accB[1];
      const int col = n0B + wn * 16 + (lane & 15);
      float hv[4];
#pragma unroll
      for (int r4 = 0; r4 < 4; ++r4) {
        const int brow = wm * 16 + (lk << 2) + r4;
        const float cn = (float)Atile[brow * 512 + ((col >> 6) << 6) +
                                      ((((col >> 3) & 7) ^ (brow & 7)) << 3) + (col & 7)];
        hv[r4] = sigm(aB[r4] + go4[r4] + bco) * cn;
        if (t == tl4[r4]) astore(lasth + (size_t)(m0B + brow) * 512 + col, hv[r4]);
      }
      __syncthreads();   // done reading Atile; reuse as exch
      float* ex2 = (float*)Atile;
#pragma unroll
      for (int r4 = 0; r4 < 4; ++r4)
        ex2[(wm * 16 + (lk << 2) + r4) * 32 + wn * 16 + (lane & 15)] = hv[r4];
      __syncthreads();
      {
        const int rowe = tid >> 3, pr = tid & 7;
#pragma unroll
        for (int z = 0; z < 2; ++z) {
          const int pp = pr + z * 8;
          const float2 hp = *(const float2*)(ex2 + rowe * 32 + (pp << 1));
          union { unsigned u; f16 h[2]; } pk;
          pk.h[0] = (f16)hp.x; pk.h[1] = (f16)hp.y;
          astore32(h16 + (size_t)(m0B + rowe) * 512 + n0B + (pp << 1), pk.u);
        }
      }
    }
    gbar(bar, 2 * t + 1, bid);
  }

  // ========== final: out[b] = sigmoid(lasth . Wd + bd) ==========
  if (bid < 64) {
    const int b = (bid << 2) + w;
    float s = 0.f;
    for (int k = lane; k < 512; k += 64) s += aload(lasth + (size_t)b * 512 + k) * Wd[k];
#pragma unroll
    for (int off = 32; off > 0; off >>= 1) s += __shfl_down(s, off);
    if (lane == 0) out[b] = 1.0f / (1.0f + __expf(-(s + bd[0])));
  }
}

extern "C" void kernel_launch(void* const* d_in, const int* in_sizes, int n_in,
                              void* d_out, int out_size, void* d_ws, size_t ws_size,
                              hipStream_t stream) {
  const float* x   = (const float*)d_in[0];
  const int*   fix = (const int*)d_in[1];
  const float* Wx  = (const float*)d_in[2];
  const float* bx  = (const float*)d_in[3];
  const float* Wh  = (const float*)d_in[4];
  const float* bh  = (const float*)d_in[5];
  const float* Wc  = (const float*)d_in[6];
  const float* bc  = (const float*)d_in[7];
  const float* Wd  = (const float*)d_in[8];
  const float* bd  = (const float*)d_in[9];
  float* out = (float*)d_out;
  char* ws = (char*)d_ws;

  f16*   xg    = (f16*)(ws);                       // 14,680,064
  f16*   Wxh   = (f16*)(ws + 14680064);            //  8,388,608
  float* xproj = (float*)(ws + 23068672);          // 29,360,128
  f16*   Wbig  = (f16*)(ws + 52428800);            //  4,194,304
  f16*   Wc2h  = (f16*)(ws + 56623104);            //    524,288
  float* biasb = (float*)(ws + 57147392);          //      8,192
  float* bxp   = (float*)(ws + 57155584);          //      8,192
  f16*   h16   = (f16*)(ws + 57163776);            //    262,144
  f16*   cb16  = (f16*)(ws + 57425920);            //    262,144
  float* linO  = (float*)(ws + 57688064);          //    524,288
  float* lasth = (float*)(ws + 58212352);          //    524,288
  int*   tlast = (int*)(ws + 58736640);            //      1,024
  int*   flag64= (int*)(ws + 58737664);            //         64
  int*   bar   = (int*)(ws + 58737728);            //      4,096

  hipMemsetAsync(h16, 0, 262144, stream);
  hipMemsetAsync(cb16, 0, 262144, stream);
  hipMemsetAsync(bar, 0, 4096, stream);

  k_prep<<<2048, 256, 0, stream>>>(Wx, bx, Wh, Wc, bh, bc, fix, Wxh, bxp, Wbig, Wc2h, biasb, flag64);
  k_gather<<<dim3(256, 4), 256, 0, stream>>>(x, fix, flag64, xg, tlast);
  k_gemm_big<<<dim3(16, 28), 256, 0, stream>>>(xg, Wxh, bxp, xproj);
  k_recur<<<NBLK, 256, 0, stream>>>(Wbig, Wc2h, biasb, bc, xproj, h16, cb16,
                                    linO, lasth, tlast, Wd, bd, out, bar);
}

// Round 6
// 235.315 us; speedup vs baseline: 5.9767x; 1.2329x over previous
//
#include <hip/hip_runtime.h>
#include <cstdint>
#include <cstddef>

#define B_   256
#define T_   14
#define INF_ 2048
#define H_   512
#define HW_  49
#define NG_  2048   /* 4*H */
#define KC_  1024   /* H (h) + H (c) */
#define NBLK 256

typedef __attribute__((ext_vector_type(8))) _Float16 f16x8;
typedef __attribute__((ext_vector_type(4))) float f32x4;
typedef _Float16 f16;

typedef const void __attribute__((address_space(1))) gvoid_t;
typedef void __attribute__((address_space(3))) svoid_t;

__device__ __forceinline__ void async16(const void* g, void* l) {
  __builtin_amdgcn_global_load_lds((gvoid_t*)g, (svoid_t*)l, 16, 0, 0);
}

__device__ __forceinline__ float sigm(float x) { return 1.0f / (1.0f + __expf(-x)); }

// relaxed agent-scope accessors: per-access coherence, NO cache-wide inv
__device__ __forceinline__ float aload(const float* p) {
  return __hip_atomic_load(p, __ATOMIC_RELAXED, __HIP_MEMORY_SCOPE_AGENT);
}
__device__ __forceinline__ unsigned long long aload64(const void* p) {
  return __hip_atomic_load((const unsigned long long*)p, __ATOMIC_RELAXED, __HIP_MEMORY_SCOPE_AGENT);
}
__device__ __forceinline__ void astore(float* p, float v) {
  __hip_atomic_store(p, v, __ATOMIC_RELAXED, __HIP_MEMORY_SCOPE_AGENT);
}
__device__ __forceinline__ void astore32(void* p, unsigned v) {
  __hip_atomic_store((unsigned*)p, v, __ATOMIC_RELAXED, __HIP_MEMORY_SCOPE_AGENT);
}

// group barrier: 32 arrivals, one counter + one generation word per group
__device__ __forceinline__ void gbarG(int* __restrict__ gb, const int p) {
  __syncthreads();
  if (threadIdx.x == 0) {
    asm volatile("s_waitcnt vmcnt(0)" ::: "memory");
    if (__hip_atomic_fetch_add(gb, 1, __ATOMIC_RELAXED, __HIP_MEMORY_SCOPE_AGENT) == (p << 5) + 31) {
      __hip_atomic_store(gb + 16, p + 1, __ATOMIC_RELAXED, __HIP_MEMORY_SCOPE_AGENT);
    } else {
      while (__hip_atomic_load(gb + 16, __ATOMIC_RELAXED, __HIP_MEMORY_SCOPE_AGENT) <= p)
        __builtin_amdgcn_s_sleep(1);
    }
  }
  __syncthreads();
}

// ---------------- prep: weight conversions (gate-interleaved n = h*4+g) ----------------
__global__ void k_prep(const float* __restrict__ Wx, const float* __restrict__ bx,
                       const float* __restrict__ Wh, const float* __restrict__ Wc,
                       const float* __restrict__ bh, const float* __restrict__ bc,
                       const int* __restrict__ fix,
                       f16* __restrict__ Wxh, float* __restrict__ bxp,
                       f16* __restrict__ Wbig, f16* __restrict__ Wc2h,
                       float* __restrict__ biasb, int* __restrict__ flag64)
{
  __shared__ int any;
  const int tid = blockIdx.x * blockDim.x + threadIdx.x;
  const int nth = gridDim.x * blockDim.x;
  if (blockIdx.x == 0) {
    if (threadIdx.x == 0) any = 0;
    __syncthreads();
    int a = 0;
    for (int j = 1 + 2 * (int)threadIdx.x; j < B_ * T_; j += 2 * (int)blockDim.x) a |= fix[j];
    if (a) any = 1;
    __syncthreads();
    if (threadIdx.x == 0) flag64[0] = (any == 0) ? 1 : 0;
  }
  for (int i = tid; i < 4 * H_ * INF_; i += nth) {
    const int n = i >> 11, k = i & 2047;
    const int g = n & 3, h = n >> 2;
    Wxh[i] = (f16)Wx[((size_t)(g * H_ + h)) * INF_ + k];
  }
  for (int i = tid; i < NG_ * KC_; i += nth) {
    const int n = i >> 10, k = i & 1023;
    const int g = n & 3, h = n >> 2;
    float v;
    if (k < H_) v = Wh[((size_t)(g * H_ + h)) * H_ + k];
    else {
      const int kk = k - H_;
      v = (g == 0) ? Wc[h * H_ + kk] : (g == 1) ? Wc[H_ * H_ + h * H_ + kk] : 0.0f;
    }
    Wbig[i] = (f16)v;
  }
  for (int i = tid; i < H_ * H_; i += nth) Wc2h[i] = (f16)Wc[2 * H_ * H_ + i];
  for (int i = tid; i < NG_; i += nth) {
    const int g = i & 3, h = i >> 2;
    biasb[i] = bh[g * H_ + h] + ((g == 0) ? bc[h] : (g == 1) ? bc[H_ + h] : 0.0f);
    bxp[i] = bx[g * H_ + h];
  }
}

// ---------------- gather: coalesced row-read, extract 14 columns from LDS ----------------
__global__ __launch_bounds__(256) void k_gather(const float* __restrict__ x,
                                                const int* __restrict__ fix,
                                                const int* __restrict__ flag64,
                                                f16* __restrict__ xg,
                                                int* __restrict__ tlast)
{
  __shared__ float rows[256 * 49];
  __shared__ int wv[T_];
  const int b = blockIdx.x;
  const int tid = threadIdx.x;
  const int is64 = flag64[0];
  if (tid < T_) wv[tid] = is64 ? fix[2 * (b * T_ + tid)] : fix[b * T_ + tid];
  __syncthreads();
  if (blockIdx.y == 0 && tid == 0) {
    int cnt = 0;
    for (int t = 0; t < T_; ++t) cnt += (wv[t] == 0);
    tlast[b] = (cnt < T_) ? (T_ - 1 - cnt) : (T_ - 1);
  }
  const float* xb = x + (size_t)b * (INF_ * HW_);
  for (int c = 0; c < 2; ++c) {
    const int ch = blockIdx.y * 2 + c;
    if (c) __syncthreads();
    const float4* src = (const float4*)(xb + (size_t)ch * 256 * 49);
    float4* dst4 = (float4*)rows;
    for (int i = tid; i < 3136; i += 256) dst4[i] = src[i];
    __syncthreads();
#pragma unroll
    for (int t = 0; t < T_; ++t)
      xg[(size_t)(b * T_ + t) * INF_ + ch * 256 + tid] = (f16)rows[tid * 49 + wv[t]];
  }
}

// ---------------- big GEMM: xproj[3584][2048] = xg @ Wxh^T + bxp ----------------
__global__ __launch_bounds__(256) void k_gemm_big(
    const f16* __restrict__ A, const f16* __restrict__ Bw,
    const float* __restrict__ bxp, float* __restrict__ Cproj)
{
  __shared__ alignas(16) f16 As[128 * 64];
  __shared__ alignas(16) f16 Bs[128 * 64];
  const int tid = threadIdx.x;
  const int lane = tid & 63;
  const int w = tid >> 6;
  const int wm = w >> 1, wn = w & 1;
  const int flat = blockIdx.y * 16 + blockIdx.x;
  const int wg = (flat & 7) * 56 + (flat >> 3);
  const int m0 = (wg >> 4) * 128, n0 = (wg & 15) * 128;
  f32x4 acc[4][4] = {};
  const int lrow = lane >> 3;
  const int kg = lane & 7;
  for (int ks = 0; ks < 2048; ks += 64) {
#pragma unroll
    for (int q = 0; q < 4; ++q) {
      const int chunk = (w << 2) + q;
      const int row = (chunk << 3) + lrow;
      const int skg = kg ^ (row & 7);
      async16(A + (size_t)(m0 + row) * 2048 + ks + (skg << 3), As + chunk * 512);
      async16(Bw + (size_t)(n0 + row) * 2048 + ks + (skg << 3), Bs + chunk * 512);
    }
    __syncthreads();
#pragma unroll
    for (int kk = 0; kk < 2; ++kk) {
      const int kgl = (kk << 2) + (lane >> 4);
      f16x8 af[4], bf[4];
#pragma unroll
      for (int mi = 0; mi < 4; ++mi) {
        const int r = (wm << 6) + (mi << 4) + (lane & 15);
        af[mi] = *(const f16x8*)(As + r * 64 + ((kgl ^ (r & 7)) << 3));
      }
#pragma unroll
      for (int ni = 0; ni < 4; ++ni) {
        const int r = (wn << 6) + (ni << 4) + (lane & 15);
        bf[ni] = *(const f16x8*)(Bs + r * 64 + ((kgl ^ (r & 7)) << 3));
      }
#pragma unroll
      for (int mi = 0; mi < 4; ++mi)
#pragma unroll
        for (int ni = 0; ni < 4; ++ni)
          acc[mi][ni] = __builtin_amdgcn_mfma_f32_16x16x32_f16(af[mi], bf[ni], acc[mi][ni], 0, 0, 0);
    }
    __syncthreads();
  }
#pragma unroll
  for (int mi = 0; mi < 4; ++mi)
#pragma unroll
    for (int ni = 0; ni < 4; ++ni)
#pragma unroll
      for (int r4 = 0; r4 < 4; ++r4) {
        const int row = m0 + (wm << 6) + (mi << 4) + ((lane >> 4) << 2) + r4;
        const int col = n0 + (wn << 6) + (ni << 4) + (lane & 15);
        Cproj[(size_t)row * 2048 + col] = acc[mi][ni][r4] + bxp[col];
      }
}

// ---------------- persistent recurrence: group-local sync, resident weights ----------------
__global__ __launch_bounds__(256, 1) void k_recur(
    const f16* __restrict__ Wbig, const f16* __restrict__ Wc2h,
    const float* __restrict__ biasb, const float* __restrict__ bc,
    const float* __restrict__ xproj, f16* __restrict__ h16,
    f16* __restrict__ cb16, float* __restrict__ lasth,
    const int* __restrict__ tlast, const float* __restrict__ Wd,
    const float* __restrict__ bd, float* __restrict__ out,
    int* __restrict__ bar)
{
  __shared__ alignas(16) f16 hT[32 * 512];    // 32 KB, h operand (staged per step)
  __shared__ alignas(16) f16 cT[32 * 512];    // 32 KB, c operand (persists A<-B)
  __shared__ alignas(16) float exch[1024];    // [cn 32x16 | go 32x16]
  __shared__ alignas(16) float ex2[1024];     // phase-B K-split partials
  const int tid = threadIdx.x, lane = tid & 63, w = tid >> 6;
  const int wm = w >> 1, wn = w & 1;
  const int lk = lane >> 4;
  const int bid = blockIdx.x;
  const int grp = bid >> 5, grank = bid & 31;
  const int m0 = grp * 32;
  const int n0A = grank * 64;   // gate cols (4 per h col)
  const int n0h = grank * 16;   // h cols
  int* const gb = bar + grp * 64;

  // ---- resident weights ----
  f16x8 wG[2][32];
#pragma unroll
  for (int ni = 0; ni < 2; ++ni) {
    const f16* src = Wbig + (size_t)(n0A + wn * 32 + ni * 16 + (lane & 15)) * 1024 + (lk << 3);
#pragma unroll
    for (int kc = 0; kc < 32; ++kc) wG[ni][kc] = *(const f16x8*)(src + kc * 32);
  }
  f16x8 wO[8];
  {
    const f16* src = Wc2h + (size_t)(n0h + (lane & 15)) * 512 + (lk << 3);
#pragma unroll
    for (int j = 0; j < 8; ++j) wO[j] = *(const f16x8*)(src + (wn * 8 + j) * 32);
  }
  // hoisted epilogue constants
  const int hq = (lane >> 2) & 3;
  const int browA = wm * 16 + (lk << 2) + (lane & 3);
  const int bgA = m0 + browA;
  float4 b4c[2];
#pragma unroll
  for (int ni = 0; ni < 2; ++ni)
    b4c[ni] = *(const float4*)(biasb + 4 * (n0h + wn * 8 + ni * 4 + hq));
  const int colg = n0h + (lane & 15);
  const float bco = bc[1024 + colg];
  int tl2[4] = {-1, -1, -1, -1};
  if (w < 2) {
#pragma unroll
    for (int r4 = 0; r4 < 4; ++r4) tl2[r4] = tlast[m0 + w * 16 + lk * 4 + r4];
  }
  // zero cT (c_{-1} = 0)
  {
    const f16x8 z = {};
#pragma unroll
    for (int j = 0; j < 8; ++j) *(f16x8*)(cT + (((j << 8) + tid) << 3)) = z;
  }
  float creg[2] = {0.f, 0.f};
  __syncthreads();

  for (int t = 0; t < T_; ++t) {
    // ===== phase A: gates GEMM over [h | c] =====
    float4 x4p[2];
#pragma unroll
    for (int ni = 0; ni < 2; ++ni)
      x4p[ni] = *(const float4*)(xproj + (size_t)(bgA * T_ + t) * 2048 +
                                 4 * (n0h + wn * 8 + ni * 4 + hq));
    // stage hT [32][512] coherently
#pragma unroll
    for (int j = 0; j < 8; ++j) {
      const int u = (j << 8) + tid;
      const int row = u >> 6, kg = u & 63;
      const f16* src = h16 + (size_t)(m0 + row) * 512 + (kg << 3);
      union { f16x8 v; unsigned long long q[2]; } u2;
      u2.q[0] = aload64(src);
      u2.q[1] = aload64(src + 4);
      *(f16x8*)(hT + row * 512 + ((kg >> 3) << 6) + (((kg & 7) ^ (row & 7)) << 3)) = u2.v;
    }
    __syncthreads();
    f32x4 acc[4][2] = {};
    {
      const int ra = wm * 16 + (lane & 15);
#pragma unroll
      for (int kc = 0; kc < 32; ++kc) {
        const int kgl = ((kc & 1) << 2) + lk;
        const f16* base = (kc < 16) ? (hT + ((kc >> 1) << 6)) : (cT + (((kc - 16) >> 1) << 6));
        const f16x8 af = *(const f16x8*)(base + ra * 512 + ((kgl ^ (ra & 7)) << 3));
        acc[kc & 3][0] = __builtin_amdgcn_mfma_f32_16x16x32_f16(af, wG[0][kc], acc[kc & 3][0], 0, 0, 0);
        acc[kc & 3][1] = __builtin_amdgcn_mfma_f32_16x16x32_f16(af, wG[1][kc], acc[kc & 3][1], 0, 0, 0);
      }
    }
    __syncthreads();
    // epilogue: quad transpose -> (i,f,o,m) per (b,h); c in registers
#pragma unroll
    for (int ni = 0; ni < 2; ++ni) {
      const f32x4 a = (acc[0][ni] + acc[1][ni]) + (acc[2][ni] + acc[3][ni]);
      float a0 = a[0], a1 = a[1], a2 = a[2], a3 = a[3];
      {
        const bool odd = lane & 1;
        float xx = odd ? a0 : a1, yy = odd ? a2 : a3;
        xx = __shfl_xor(xx, 1); yy = __shfl_xor(yy, 1);
        if (odd) { a0 = xx; a2 = yy; } else { a1 = xx; a3 = yy; }
      }
      {
        const bool hi = lane & 2;
        float xx = hi ? a0 : a2, yy = hi ? a1 : a3;
        xx = __shfl_xor(xx, 2); yy = __shfl_xor(yy, 2);
        if (hi) { a0 = xx; a1 = yy; } else { a2 = xx; a3 = yy; }
      }
      const int hl = wn * 8 + ni * 4 + hq;
      const float gi = a0 + b4c[ni].x + x4p[ni].x;
      const float gf = a1 + b4c[ni].y + x4p[ni].y;
      const float go = a2 + b4c[ni].z + x4p[ni].z;
      const float gm = a3 + b4c[ni].w + x4p[ni].w;
      const float cn = sigm(gi) * tanhf(gm) + sigm(gf) * creg[ni];
      creg[ni] = cn;
      exch[browA * 16 + hl] = cn;
      exch[512 + browA * 16 + hl] = go;
    }
    __syncthreads();
    {
      const int rowe = tid >> 3, pr = tid & 7;
      const float2 cp = *(const float2*)(exch + rowe * 16 + (pr << 1));
      union { unsigned u; f16 h2[2]; } pk;
      pk.h2[0] = (f16)cp.x; pk.h2[1] = (f16)cp.y;
      astore32(cb16 + (size_t)(m0 + rowe) * 512 + n0h + (pr << 1), pk.u);
    }
    gbarG(gb, 2 * t);

    // ===== phase B: o-peephole GEMM + h write =====
    // stage cT [32][512] (new c; persists as next step's c operand)
#pragma unroll
    for (int j = 0; j < 8; ++j) {
      const int u = (j << 8) + tid;
      const int row = u >> 6, kg = u & 63;
      const f16* src = cb16 + (size_t)(m0 + row) * 512 + (kg << 3);
      union { f16x8 v; unsigned long long q[2]; } u2;
      u2.q[0] = aload64(src);
      u2.q[1] = aload64(src + 4);
      *(f16x8*)(cT + row * 512 + ((kg >> 3) << 6) + (((kg & 7) ^ (row & 7)) << 3)) = u2.v;
    }
    __syncthreads();
    f32x4 accB[2] = {};
    {
      const int ra2 = wm * 16 + (lane & 15);
#pragma unroll
      for (int j = 0; j < 8; ++j) {
        const int kc = wn * 8 + j;
        const int kgl = ((kc & 1) << 2) + lk;
        const f16x8 af = *(const f16x8*)(cT + ra2 * 512 + ((kc >> 1) << 6) + ((kgl ^ (ra2 & 7)) << 3));
        accB[j & 1] = __builtin_amdgcn_mfma_f32_16x16x32_f16(af, wO[j], accB[j & 1], 0, 0, 0);
      }
    }
    {
      const f32x4 s2 = accB[0] + accB[1];
#pragma unroll
      for (int r4 = 0; r4 < 4; ++r4)
        ex2[w * 256 + (lk * 4 + r4) * 16 + (lane & 15)] = s2[r4];
    }
    __syncthreads();
    if (w < 2) {
#pragma unroll
      for (int r4 = 0; r4 < 4; ++r4) {
        const int brow = w * 16 + lk * 4 + r4;
        const int idx = (lk * 4 + r4) * 16 + (lane & 15);
        const float sum = ex2[(2 * w) * 256 + idx] + ex2[(2 * w + 1) * 256 + idx];
        const float go = exch[512 + brow * 16 + (lane & 15)];
        const float cn = (float)cT[brow * 512 + ((colg >> 6) << 6) +
                                   ((((colg >> 3) & 7) ^ (brow & 7)) << 3) + (colg & 7)];
        const float hv = sigm(sum + go + bco) * cn;
        const float hvo = __shfl_xor(hv, 1);
        if (!(lane & 1)) {
          union { unsigned u; f16 h2[2]; } pk;
          pk.h2[0] = (f16)hv; pk.h2[1] = (f16)hvo;
          astore32(h16 + (size_t)(m0 + brow) * 512 + (colg & ~1), pk.u);
        }
        if (t == tl2[r4]) astore(lasth + (size_t)(m0 + brow) * 512 + colg, hv);
      }
    }
    gbarG(gb, 2 * t + 1);
  }

  // ===== final: out[b] = sigmoid(lasth . Wd + bd), one row per block =====
  if (w == 0) {
    const int b = m0 + grank;
    float s = 0.f;
#pragma unroll
    for (int k = lane; k < 512; k += 64) s += aload(lasth + (size_t)b * 512 + k) * Wd[k];
#pragma unroll
    for (int off = 32; off > 0; off >>= 1) s += __shfl_down(s, off);
    if (lane == 0) out[b] = 1.0f / (1.0f + __expf(-(s + bd[0])));
  }
}

extern "C" void kernel_launch(void* const* d_in, const int* in_sizes, int n_in,
                              void* d_out, int out_size, void* d_ws, size_t ws_size,
                              hipStream_t stream) {
  const float* x   = (const float*)d_in[0];
  const int*   fix = (const int*)d_in[1];
  const float* Wx  = (const float*)d_in[2];
  const float* bx  = (const float*)d_in[3];
  const float* Wh  = (const float*)d_in[4];
  const float* bh  = (const float*)d_in[5];
  const float* Wc  = (const float*)d_in[6];
  const float* bc  = (const float*)d_in[7];
  const float* Wd  = (const float*)d_in[8];
  const float* bd  = (const float*)d_in[9];
  float* out = (float*)d_out;
  char* ws = (char*)d_ws;

  f16*   xg    = (f16*)(ws);                       // 14,680,064
  f16*   Wxh   = (f16*)(ws + 14680064);            //  8,388,608
  float* xproj = (float*)(ws + 23068672);          // 29,360,128
  f16*   Wbig  = (f16*)(ws + 52428800);            //  4,194,304
  f16*   Wc2h  = (f16*)(ws + 56623104);            //    524,288
  float* biasb = (float*)(ws + 57147392);          //      8,192
  float* bxp   = (float*)(ws + 57155584);          //      8,192
  f16*   h16   = (f16*)(ws + 57163776);            //    262,144
  f16*   cb16  = (f16*)(ws + 57425920);            //    262,144
  float* lasth = (float*)(ws + 57688064);          //    524,288
  int*   tlast = (int*)(ws + 58212352);            //      1,024
  int*   flag64= (int*)(ws + 58213376);            //         64
  int*   bar   = (int*)(ws + 58213440);            //      4,096

  hipMemsetAsync(h16, 0, 262144, stream);
  hipMemsetAsync(cb16, 0, 262144, stream);
  hipMemsetAsync(bar, 0, 4096, stream);

  k_prep<<<2048, 256, 0, stream>>>(Wx, bx, Wh, Wc, bh, bc, fix, Wxh, bxp, Wbig, Wc2h, biasb, flag64);
  k_gather<<<dim3(256, 4), 256, 0, stream>>>(x, fix, flag64, xg, tlast);
  k_gemm_big<<<dim3(16, 28), 256, 0, stream>>>(xg, Wxh, bxp, xproj);
  k_recur<<<NBLK, 256, 0, stream>>>(Wbig, Wc2h, biasb, bc, xproj, h16, cb16,
                                    lasth, tlast, Wd, bd, out, bar);
}

// Round 7
// 217.882 us; speedup vs baseline: 6.4549x; 1.0800x over previous
//
#include <hip/hip_runtime.h>
#include <cstdint>
#include <cstddef>

#define B_   256
#define T_   14
#define INF_ 2048
#define H_   512
#define HW_  49
#define NG_  2048   /* 4*H */
#define KC_  1024   /* H (h) + H (c) */
#define NBLK 256

typedef __attribute__((ext_vector_type(8))) _Float16 f16x8;
typedef __attribute__((ext_vector_type(4))) float f32x4;
typedef _Float16 f16;

typedef const void __attribute__((address_space(1))) gvoid_t;
typedef void __attribute__((address_space(3))) svoid_t;

__device__ __forceinline__ void async16(const void* g, void* l) {
  __builtin_amdgcn_global_load_lds((gvoid_t*)g, (svoid_t*)l, 16, 0, 0);
}

__device__ __forceinline__ float sigm(float x) { return 1.0f / (1.0f + __expf(-x)); }

// relaxed agent-scope accessors: per-access coherence, NO cache-wide inv
__device__ __forceinline__ float aload(const float* p) {
  return __hip_atomic_load(p, __ATOMIC_RELAXED, __HIP_MEMORY_SCOPE_AGENT);
}
__device__ __forceinline__ unsigned long long aload64(const void* p) {
  return __hip_atomic_load((const unsigned long long*)p, __ATOMIC_RELAXED, __HIP_MEMORY_SCOPE_AGENT);
}
__device__ __forceinline__ void astore(float* p, float v) {
  __hip_atomic_store(p, v, __ATOMIC_RELAXED, __HIP_MEMORY_SCOPE_AGENT);
}
__device__ __forceinline__ void astore32(void* p, unsigned v) {
  __hip_atomic_store((unsigned*)p, v, __ATOMIC_RELAXED, __HIP_MEMORY_SCOPE_AGENT);
}

// slot barrier: producer stamps its own slot; consumers poll all 32 slots
__device__ __forceinline__ void waitSlots(const int* slots, const int target) {
  const int* p = slots + (threadIdx.x & 31);
  for (;;) {
    const int v = __hip_atomic_load(p, __ATOMIC_RELAXED, __HIP_MEMORY_SCOPE_AGENT);
    if (__all(v >= target)) break;
    __builtin_amdgcn_s_sleep(1);
  }
}

// ---------------- prep: weight conversions (gate-interleaved n = h*4+g) ----------------
__global__ void k_prep(const float* __restrict__ Wx, const float* __restrict__ bx,
                       const float* __restrict__ Wh, const float* __restrict__ Wc,
                       const float* __restrict__ bh, const float* __restrict__ bc,
                       const int* __restrict__ fix,
                       f16* __restrict__ Wxh, float* __restrict__ bxp,
                       f16* __restrict__ Wbig, f16* __restrict__ Wc2h,
                       float* __restrict__ biasb, int* __restrict__ flag64)
{
  __shared__ int any;
  const int tid = blockIdx.x * blockDim.x + threadIdx.x;
  const int nth = gridDim.x * blockDim.x;
  if (blockIdx.x == 0) {
    if (threadIdx.x == 0) any = 0;
    __syncthreads();
    int a = 0;
    for (int j = 1 + 2 * (int)threadIdx.x; j < B_ * T_; j += 2 * (int)blockDim.x) a |= fix[j];
    if (a) any = 1;
    __syncthreads();
    if (threadIdx.x == 0) flag64[0] = (any == 0) ? 1 : 0;
  }
  for (int i = tid; i < 4 * H_ * INF_; i += nth) {
    const int n = i >> 11, k = i & 2047;
    const int g = n & 3, h = n >> 2;
    Wxh[i] = (f16)Wx[((size_t)(g * H_ + h)) * INF_ + k];
  }
  for (int i = tid; i < NG_ * KC_; i += nth) {
    const int n = i >> 10, k = i & 1023;
    const int g = n & 3, h = n >> 2;
    float v;
    if (k < H_) v = Wh[((size_t)(g * H_ + h)) * H_ + k];
    else {
      const int kk = k - H_;
      v = (g == 0) ? Wc[h * H_ + kk] : (g == 1) ? Wc[H_ * H_ + h * H_ + kk] : 0.0f;
    }
    Wbig[i] = (f16)v;
  }
  for (int i = tid; i < H_ * H_; i += nth) Wc2h[i] = (f16)Wc[2 * H_ * H_ + i];
  for (int i = tid; i < NG_; i += nth) {
    const int g = i & 3, h = i >> 2;
    biasb[i] = bh[g * H_ + h] + ((g == 0) ? bc[h] : (g == 1) ? bc[H_ + h] : 0.0f);
    bxp[i] = bx[g * H_ + h];
  }
}

// ---------------- gather: coalesced row-read, extract 14 columns from LDS ----------------
__global__ __launch_bounds__(256) void k_gather(const float* __restrict__ x,
                                                const int* __restrict__ fix,
                                                const int* __restrict__ flag64,
                                                f16* __restrict__ xg,
                                                int* __restrict__ tlast)
{
  __shared__ float rows[256 * 49];
  __shared__ int wv[T_];
  const int b = blockIdx.x;
  const int tid = threadIdx.x;
  const int is64 = flag64[0];
  if (tid < T_) wv[tid] = is64 ? fix[2 * (b * T_ + tid)] : fix[b * T_ + tid];
  __syncthreads();
  if (blockIdx.y == 0 && tid == 0) {
    int cnt = 0;
    for (int t = 0; t < T_; ++t) cnt += (wv[t] == 0);
    tlast[b] = (cnt < T_) ? (T_ - 1 - cnt) : (T_ - 1);
  }
  const float* xb = x + (size_t)b * (INF_ * HW_);
  for (int c = 0; c < 2; ++c) {
    const int ch = blockIdx.y * 2 + c;
    if (c) __syncthreads();
    const float4* src = (const float4*)(xb + (size_t)ch * 256 * 49);
    float4* dst4 = (float4*)rows;
    for (int i = tid; i < 3136; i += 256) dst4[i] = src[i];
    __syncthreads();
#pragma unroll
    for (int t = 0; t < T_; ++t)
      xg[(size_t)(b * T_ + t) * INF_ + ch * 256 + tid] = (f16)rows[tid * 49 + wv[t]];
  }
}

// ---------------- big GEMM: xproj[3584][2048] = xg @ Wxh^T + bxp ----------------
__global__ __launch_bounds__(256) void k_gemm_big(
    const f16* __restrict__ A, const f16* __restrict__ Bw,
    const float* __restrict__ bxp, float* __restrict__ Cproj)
{
  __shared__ alignas(16) f16 As[128 * 64];
  __shared__ alignas(16) f16 Bs[128 * 64];
  const int tid = threadIdx.x;
  const int lane = tid & 63;
  const int w = tid >> 6;
  const int wm = w >> 1, wn = w & 1;
  const int flat = blockIdx.y * 16 + blockIdx.x;
  const int wg = (flat & 7) * 56 + (flat >> 3);
  const int m0 = (wg >> 4) * 128, n0 = (wg & 15) * 128;
  f32x4 acc[4][4] = {};
  const int lrow = lane >> 3;
  const int kg = lane & 7;
  for (int ks = 0; ks < 2048; ks += 64) {
#pragma unroll
    for (int q = 0; q < 4; ++q) {
      const int chunk = (w << 2) + q;
      const int row = (chunk << 3) + lrow;
      const int skg = kg ^ (row & 7);
      async16(A + (size_t)(m0 + row) * 2048 + ks + (skg << 3), As + chunk * 512);
      async16(Bw + (size_t)(n0 + row) * 2048 + ks + (skg << 3), Bs + chunk * 512);
    }
    __syncthreads();
#pragma unroll
    for (int kk = 0; kk < 2; ++kk) {
      const int kgl = (kk << 2) + (lane >> 4);
      f16x8 af[4], bf[4];
#pragma unroll
      for (int mi = 0; mi < 4; ++mi) {
        const int r = (wm << 6) + (mi << 4) + (lane & 15);
        af[mi] = *(const f16x8*)(As + r * 64 + ((kgl ^ (r & 7)) << 3));
      }
#pragma unroll
      for (int ni = 0; ni < 4; ++ni) {
        const int r = (wn << 6) + (ni << 4) + (lane & 15);
        bf[ni] = *(const f16x8*)(Bs + r * 64 + ((kgl ^ (r & 7)) << 3));
      }
#pragma unroll
      for (int mi = 0; mi < 4; ++mi)
#pragma unroll
        for (int ni = 0; ni < 4; ++ni)
          acc[mi][ni] = __builtin_amdgcn_mfma_f32_16x16x32_f16(af[mi], bf[ni], acc[mi][ni], 0, 0, 0);
    }
    __syncthreads();
  }
#pragma unroll
  for (int mi = 0; mi < 4; ++mi)
#pragma unroll
    for (int ni = 0; ni < 4; ++ni)
#pragma unroll
      for (int r4 = 0; r4 < 4; ++r4) {
        const int row = m0 + (wm << 6) + (mi << 4) + ((lane >> 4) << 2) + r4;
        const int col = n0 + (wn << 6) + (ni << 4) + (lane & 15);
        Cproj[(size_t)row * 2048 + col] = acc[mi][ni][r4] + bxp[col];
      }
}

// ---------------- persistent recurrence: dual-tile pipeline, slot barriers ----------------
__global__ __launch_bounds__(256, 1) void k_recur(
    const f16* __restrict__ Wbig, const f16* __restrict__ Wc2h,
    const float* __restrict__ biasb, const float* __restrict__ bc,
    const float* __restrict__ xproj, f16* __restrict__ h16,
    f16* __restrict__ cb16, float* __restrict__ lasth,
    const int* __restrict__ tlast, const float* __restrict__ Wd,
    const float* __restrict__ bd, float* __restrict__ out,
    int* __restrict__ bar)
{
  __shared__ alignas(16) f16 hT[2][16 * 512];   // 16 KB each
  __shared__ alignas(16) f16 cT[2][16 * 512];   // persists B(t) -> A(t+1)
  __shared__ alignas(16) float exCN[256];       // cn scratch (reused per tile)
  __shared__ alignas(16) float exGO[2][256];    // go, survives A -> B per tile
  __shared__ alignas(16) float ex2[4 * 256];    // B-phase K-split partials
  const int tid = threadIdx.x, lane = tid & 63, w = tid >> 6;
  const int lk = lane >> 4;
  const int bid = blockIdx.x;
  const int pair = bid >> 5, grank = bid & 31;
  const int n0A = grank * 64, n0h = grank * 16;
  const int m0t[2] = {pair * 32, pair * 32 + 16};
  int* const sl[2] = {bar + (2 * pair) * 64, bar + (2 * pair + 1) * 64};

  // ---- resident weights ----
  f16x8 wG[32];   // gates B-operand: this wave's 16 gate-cols x K=1024
  {
    const f16* src = Wbig + (size_t)(n0A + w * 16 + (lane & 15)) * 1024 + (lk << 3);
#pragma unroll
    for (int kc = 0; kc < 32; ++kc) wG[kc] = *(const f16x8*)(src + kc * 32);
  }
  f16x8 wO[4];    // o-peephole: 16 h-cols x this wave's K-chunk (128)
  {
    const f16* src = Wc2h + (size_t)(n0h + (lane & 15)) * 512 + (lk << 3);
#pragma unroll
    for (int j = 0; j < 4; ++j) wO[j] = *(const f16x8*)(src + (w * 4 + j) * 32);
  }
  // hoisted constants
  const int hq = (lane >> 2) & 3;
  const int browA = (lk << 2) + (lane & 3);        // A-epilogue batch row (0..15)
  const int hlA = w * 4 + hq;                      // A-epilogue h-col within slice
  const float4 b4c = *(const float4*)(biasb + 4 * (n0h + hlA));
  const int rowB = tid >> 4, colB = tid & 15;      // B-epilogue (row, h-col)
  const float bco = bc[1024 + n0h + colB];
  const int tlB[2] = {tlast[m0t[0] + rowB], tlast[m0t[1] + rowB]};
  // zero cT (c_{-1} = 0)
  {
    const f16x8 z = {};
#pragma unroll
    for (int j = 0; j < 8; ++j) *(f16x8*)(&cT[0][0] + (((j << 8) + tid) << 3)) = z;
  }
  float creg[2] = {0.f, 0.f};
  __syncthreads();

  for (int t = 0; t < T_; ++t) {
    // prefetch xproj for both tiles (read-only, cached, in flight across waits)
    float4 x4p[2];
#pragma unroll
    for (int tt = 0; tt < 2; ++tt)
      x4p[tt] = *(const float4*)(xproj + (size_t)((m0t[tt] + browA) * T_ + t) * 2048 +
                                 4 * (n0h + hlA));

#pragma unroll
    for (int tt = 0; tt < 2; ++tt) {
      // ===== phase A(tile tt): gates GEMM over [h | c] =====
      if (t) waitSlots(sl[tt], 2 * t);
      // stage hT[tt] [16][512] coherently (4 units of 8 f16 per thread)
#pragma unroll
      for (int j = 0; j < 4; ++j) {
        const int u = (j << 8) + tid;
        const int row = u >> 6, kg = u & 63;
        const f16* src = h16 + (size_t)(m0t[tt] + row) * 512 + (kg << 3);
        union { f16x8 v; unsigned long long q[2]; } u2;
        u2.q[0] = aload64(src);
        u2.q[1] = aload64(src + 4);
        *(f16x8*)(&hT[tt][0] + row * 512 + ((kg >> 3) << 6) + (((kg & 7) ^ (row & 7)) << 3)) = u2.v;
      }
      __syncthreads();
      f32x4 acc[2] = {};
      {
        const int ra = lane & 15;
#pragma unroll
        for (int kc = 0; kc < 32; ++kc) {
          const int kgl = ((kc & 1) << 2) + lk;
          const f16* base = (kc < 16) ? (&hT[tt][0] + ((kc >> 1) << 6))
                                      : (&cT[tt][0] + (((kc - 16) >> 1) << 6));
          const f16x8 af = *(const f16x8*)(base + ra * 512 + ((kgl ^ (ra & 7)) << 3));
          acc[kc & 1] = __builtin_amdgcn_mfma_f32_16x16x32_f16(af, wG[kc], acc[kc & 1], 0, 0, 0);
        }
      }
      // epilogue: quad transpose -> (i,f,o,m) per (b,h)
      {
        const f32x4 a = acc[0] + acc[1];
        float a0 = a[0], a1 = a[1], a2 = a[2], a3 = a[3];
        {
          const bool odd = lane & 1;
          float xx = odd ? a0 : a1, yy = odd ? a2 : a3;
          xx = __shfl_xor(xx, 1); yy = __shfl_xor(yy, 1);
          if (odd) { a0 = xx; a2 = yy; } else { a1 = xx; a3 = yy; }
        }
        {
          const bool hi = lane & 2;
          float xx = hi ? a0 : a2, yy = hi ? a1 : a3;
          xx = __shfl_xor(xx, 2); yy = __shfl_xor(yy, 2);
          if (hi) { a0 = xx; a1 = yy; } else { a2 = xx; a3 = yy; }
        }
        const float gi = a0 + b4c.x + x4p[tt].x;
        const float gf = a1 + b4c.y + x4p[tt].y;
        const float go = a2 + b4c.z + x4p[tt].z;
        const float gm = a3 + b4c.w + x4p[tt].w;
        const float cn = sigm(gi) * tanhf(gm) + sigm(gf) * creg[tt];
        creg[tt] = cn;
        exCN[browA * 16 + hlA] = cn;
        exGO[tt][browA * 16 + hlA] = go;
      }
      __syncthreads();
      if (tid < 128) {   // pack + store c (16 rows x 8 col-pairs)
        const int rowe = tid >> 3, pr = tid & 7;
        const float2 cp = *(const float2*)(exCN + rowe * 16 + (pr << 1));
        union { unsigned u; f16 h2[2]; } pk;
        pk.h2[0] = (f16)cp.x; pk.h2[1] = (f16)cp.y;
        astore32(cb16 + (size_t)(m0t[tt] + rowe) * 512 + n0h + (pr << 1), pk.u);
      }
      __syncthreads();   // drains all waves' vmcnt -> c globally visible
      if (tid == 0)
        __hip_atomic_store(sl[tt] + grank, 2 * t + 1, __ATOMIC_RELAXED, __HIP_MEMORY_SCOPE_AGENT);
    }

#pragma unroll
    for (int tt = 0; tt < 2; ++tt) {
      // ===== phase B(tile tt): o-peephole GEMM + h write =====
      waitSlots(sl[tt], 2 * t + 1);
      // stage cT[tt] (new c; persists as next step's A operand)
#pragma unroll
      for (int j = 0; j < 4; ++j) {
        const int u = (j << 8) + tid;
        const int row = u >> 6, kg = u & 63;
        const f16* src = cb16 + (size_t)(m0t[tt] + row) * 512 + (kg << 3);
        union { f16x8 v; unsigned long long q[2]; } u2;
        u2.q[0] = aload64(src);
        u2.q[1] = aload64(src + 4);
        *(f16x8*)(&cT[tt][0] + row * 512 + ((kg >> 3) << 6) + (((kg & 7) ^ (row & 7)) << 3)) = u2.v;
      }
      __syncthreads();
      f32x4 accB = {};
      {
        const int ra = lane & 15;
#pragma unroll
        for (int j = 0; j < 4; ++j) {
          const int kc = w * 4 + j;
          const int kgl = ((kc & 1) << 2) + lk;
          const f16x8 af = *(const f16x8*)(&cT[tt][0] + ra * 512 + ((kc >> 1) << 6) +
                                           ((kgl ^ (ra & 7)) << 3));
          accB = __builtin_amdgcn_mfma_f32_16x16x32_f16(af, wO[j], accB, 0, 0, 0);
        }
      }
#pragma unroll
      for (int r4 = 0; r4 < 4; ++r4)
        ex2[w * 256 + ((lk << 2) + r4) * 16 + (lane & 15)] = accB[r4];
      __syncthreads();
      {
        const int ib = rowB * 16 + colB;
        const float sum = (ex2[ib] + ex2[256 + ib]) + (ex2[512 + ib] + ex2[768 + ib]);
        const int cg = n0h + colB;
        const float cn = (float)cT[tt][rowB * 512 + ((cg >> 6) << 6) +
                                       ((((cg >> 3) & 7) ^ (rowB & 7)) << 3) + (cg & 7)];
        const float hv = sigm(sum + exGO[tt][ib] + bco) * cn;
        const float hvo = __shfl_xor(hv, 1);
        if (!(tid & 1)) {
          union { unsigned u; f16 h2[2]; } pk;
          pk.h2[0] = (f16)hv; pk.h2[1] = (f16)hvo;
          astore32(h16 + (size_t)(m0t[tt] + rowB) * 512 + (cg & ~1), pk.u);
        }
        if (t == tlB[tt]) astore(lasth + (size_t)(m0t[tt] + rowB) * 512 + cg, hv);
      }
      __syncthreads();   // drains vmcnt -> h globally visible
      if (tid == 0)
        __hip_atomic_store(sl[tt] + grank, 2 * t + 2, __ATOMIC_RELAXED, __HIP_MEMORY_SCOPE_AGENT);
    }
  }

  // ===== final: out[b] = sigmoid(lasth . Wd + bd), one row per block =====
  waitSlots(sl[0], 2 * T_);
  waitSlots(sl[1], 2 * T_);
  if (w == 0) {
    const int b = pair * 32 + grank;
    float s = 0.f;
#pragma unroll
    for (int k = lane; k < 512; k += 64) s += aload(lasth + (size_t)b * 512 + k) * Wd[k];
#pragma unroll
    for (int off = 32; off > 0; off >>= 1) s += __shfl_down(s, off);
    if (lane == 0) out[b] = 1.0f / (1.0f + __expf(-(s + bd[0])));
  }
}

extern "C" void kernel_launch(void* const* d_in, const int* in_sizes, int n_in,
                              void* d_out, int out_size, void* d_ws, size_t ws_size,
                              hipStream_t stream) {
  const float* x   = (const float*)d_in[0];
  const int*   fix = (const int*)d_in[1];
  const float* Wx  = (const float*)d_in[2];
  const float* bx  = (const float*)d_in[3];
  const float* Wh  = (const float*)d_in[4];
  const float* bh  = (const float*)d_in[5];
  const float* Wc  = (const float*)d_in[6];
  const float* bc  = (const float*)d_in[7];
  const float* Wd  = (const float*)d_in[8];
  const float* bd  = (const float*)d_in[9];
  float* out = (float*)d_out;
  char* ws = (char*)d_ws;

  f16*   xg    = (f16*)(ws);                       // 14,680,064
  f16*   Wxh   = (f16*)(ws + 14680064);            //  8,388,608
  float* xproj = (float*)(ws + 23068672);          // 29,360,128
  f16*   Wbig  = (f16*)(ws + 52428800);            //  4,194,304
  f16*   Wc2h  = (f16*)(ws + 56623104);            //    524,288
  float* biasb = (float*)(ws + 57147392);          //      8,192
  float* bxp   = (float*)(ws + 57155584);          //      8,192
  f16*   h16   = (f16*)(ws + 57163776);            //    262,144
  f16*   cb16  = (f16*)(ws + 57425920);            //    262,144
  float* lasth = (float*)(ws + 57688064);          //    524,288
  int*   tlast = (int*)(ws + 58212352);            //      1,024
  int*   flag64= (int*)(ws + 58213376);            //         64
  int*   bar   = (int*)(ws + 58213440);            //      4,096

  hipMemsetAsync(h16, 0, 262144, stream);
  hipMemsetAsync(cb16, 0, 262144, stream);
  hipMemsetAsync(bar, 0, 4096, stream);

  k_prep<<<2048, 256, 0, stream>>>(Wx, bx, Wh, Wc, bh, bc, fix, Wxh, bxp, Wbig, Wc2h, biasb, flag64);
  k_gather<<<dim3(256, 4), 256, 0, stream>>>(x, fix, flag64, xg, tlast);
  k_gemm_big<<<dim3(16, 28), 256, 0, stream>>>(xg, Wxh, bxp, xproj);
  k_recur<<<NBLK, 256, 0, stream>>>(Wbig, Wc2h, biasb, bc, xproj, h16, cb16,
                                    lasth, tlast, Wd, bd, out, bar);
}